// Round 1
// baseline (37741.867 us; speedup 1.0000x reference)
//
#include <hip/hip_runtime.h>
#include <math.h>

#define TSTEPS 1024
#define NWG_TOT 256

// workspace layout (float offsets)
#define WS_BAR    0
#define WS_WEFF_C 64
#define WS_WEFF_X (WS_WEFF_C + 2048*10)
#define WS_BIAS_C (WS_WEFF_X + 2048*6)
#define WS_BIAS_X (WS_BIAS_C + 64*2048)
#define WS_H_C    (WS_BIAS_X + 64*2048)
#define WS_H_X    (WS_H_C + 3*64*512)
#define WS_WPACK  (WS_H_X + 3*64*512)
#define WS_TOTAL  (WS_WPACK + 2*128*512*16)

__device__ __forceinline__ float sigm(float v) { return 1.f / (1.f + __expf(-v)); }

// ---------------- setup kernel 1: effective input weights + per-batch bias ----------------
// Weff[g][j]   = sum_d w_ih[g][d] * w_emb[d][j]
// biasE[b][g]  = b_ih[g]+b_hh[g] + sum_d w_ih[g][d]*b_emb[d] + sum_c w_ih[g][512+c]*ctx[b][c]
__global__ void setup_weff_bias(const float* __restrict__ ctx,
                                const float* __restrict__ we_c, const float* __restrict__ be_c,
                                const float* __restrict__ we_x, const float* __restrict__ be_x,
                                const float* __restrict__ wih_c, const float* __restrict__ bih_c, const float* __restrict__ bhh_c,
                                const float* __restrict__ wih_x, const float* __restrict__ bih_x, const float* __restrict__ bhh_x,
                                float* __restrict__ weff_c_o, float* __restrict__ weff_x_o,
                                float* __restrict__ biasE_c_o, float* __restrict__ biasE_x_o)
{
    const int g = blockIdx.x;
    const int lstm = blockIdx.y;
    const int tid = threadIdx.x;
    const float* wih  = lstm ? wih_x : wih_c;
    const float* wemb = lstm ? we_x  : we_c;
    const float* bemb = lstm ? be_x  : be_c;
    const int NW = lstm ? 6 : 10;
    float* weff  = lstm ? weff_x_o  : weff_c_o;
    float* biasE = lstm ? biasE_x_o : biasE_c_o;
    const float* wg_ = wih + (size_t)g * 768;

    __shared__ float s_bias0;

    if (tid < NW) {
        float s = 0.f;
        for (int d = 0; d < 512; ++d) s = fmaf(wg_[d], wemb[d * NW + tid], s);
        weff[g * NW + tid] = s;
    }
    if (tid >= 64 && tid < 128) {
        int l = tid - 64;
        float s = 0.f;
        for (int i = 0; i < 8; ++i) { int d = l + i * 64; s = fmaf(wg_[d], bemb[d], s); }
        for (int m = 1; m < 64; m <<= 1) s += __shfl_xor(s, m);
        if (l == 0) s_bias0 = s;
    }
    __syncthreads();
    if (tid >= 128 && tid < 192) {
        int b = tid - 128;
        float s = s_bias0 + (lstm ? (bih_x[g] + bhh_x[g]) : (bih_c[g] + bhh_c[g]));
        const float* cb = ctx + b * 256;
        const float* wc = wg_ + 512;
        for (int c = 0; c < 256; ++c) s = fmaf(wc[c], cb[c], s);
        biasE[b * 2048 + g] = s;
    }
}

// ---------------- setup kernel 2: pack recurrent weights per WG as [k][16 rows] ----------------
// row order r: r = kk*4 + q  <->  w_hh row (q*512 + wl*4 + kk)
__global__ void setup_wpack(const float* __restrict__ whh_c, const float* __restrict__ whh_x,
                            float* __restrict__ wpack)
{
    int idx = blockIdx.x * 256 + threadIdx.x;   // 2*128*512*16 total
    int r = idx & 15;
    int k = (idx >> 4) & 511;
    int wl = (idx >> 13) & 127;
    int lstm = idx >> 20;
    const float* whh = lstm ? whh_x : whh_c;
    int q = r & 3, kk = r >> 2;
    int grow = q * 512 + wl * 4 + kk;
    wpack[idx] = whh[(size_t)grow * 512 + k];
}

// ---------------- grid barrier (agent scope, centralized, monotonic gen) ----------------
__device__ __forceinline__ void gbar(unsigned* cnt, unsigned* gen, unsigned target)
{
    __syncthreads();
    if (threadIdx.x == 0) {
        __builtin_amdgcn_fence(__ATOMIC_RELEASE, "agent");
        unsigned prev = __hip_atomic_fetch_add(cnt, 1u, __ATOMIC_RELAXED, __HIP_MEMORY_SCOPE_AGENT);
        if (prev == (unsigned)(NWG_TOT - 1)) {
            __hip_atomic_store(cnt, 0u, __ATOMIC_RELAXED, __HIP_MEMORY_SCOPE_AGENT);
            __hip_atomic_fetch_add(gen, 1u, __ATOMIC_RELEASE, __HIP_MEMORY_SCOPE_AGENT);
        } else {
            while (__hip_atomic_load(gen, __ATOMIC_RELAXED, __HIP_MEMORY_SCOPE_AGENT) < target) {
                __builtin_amdgcn_s_sleep(2);
            }
        }
        __builtin_amdgcn_fence(__ATOMIC_ACQUIRE, "agent");
    }
    __syncthreads();
}

// ---------------- main persistent cooperative kernel ----------------
// 256 WGs x 256 threads. WG (lstm, wl): owns k-slots wl*4..wl*4+3, i.e. gate rows
// {q*512 + wl*4 + kk : q<4, kk<4}. One barrier per timestep. Heads fused (cmd at t-1, coord at t-2).
__global__ __launch_bounds__(256, 1) void lstm_main(
    const float* __restrict__ x,
    const float* __restrict__ wpack,
    const float* __restrict__ weff_c, const float* __restrict__ weff_x,
    const float* __restrict__ biasE_c, const float* __restrict__ biasE_x,
    float* __restrict__ h_c, float* __restrict__ h_x,
    unsigned* __restrict__ bar,
    const float* __restrict__ w_out_cmd, const float* __restrict__ b_out_cmd,
    const float* __restrict__ w_out_coord, const float* __restrict__ b_out_coord,
    const float* __restrict__ scale_p,
    float* __restrict__ out)
{
    __shared__ float hT[128][65];        // h chunk, transposed [k][b]
    __shared__ float gparts[16][4][65];  // partial gates [row][wave][b]
    __shared__ float x_lds[64][16];
    __shared__ float bias_lds[64][16];
    __shared__ float weff_lds[16][10];
    __shared__ float c_lds[64][4];

    const int tid = threadIdx.x;
    const int wg = blockIdx.x;
    const int lstm = wg >> 7;
    const int wl = wg & 127;
    const int NW = lstm ? 6 : 10;
    const int xoff = lstm ? 10 : 0;

    float* hbase = lstm ? h_x : h_c;
    const float* biasE = lstm ? biasE_x : biasE_c;
    const float* weff  = lstm ? weff_x : weff_c;
    const float* wpack_wg = wpack + ((size_t)(lstm * 128 + wl) << 13);  // 512*16 floats per WG
    unsigned* bar_cnt = bar;
    unsigned* bar_gen = bar + 16;

    // ---- one-time staging ----
    for (int i = tid; i < 64 * 16; i += 256) {
        int b = i >> 4, r = i & 15;
        int q = r & 3, kk = r >> 2;
        int g = q * 512 + wl * 4 + kk;
        bias_lds[b][r] = biasE[b * 2048 + g];
    }
    for (int i = tid; i < 16 * NW; i += 256) {
        int r = i / NW, j = i - r * NW;
        int q = r & 3, kk = r >> 2;
        int g = q * 512 + wl * 4 + kk;
        weff_lds[r][j] = weff[g * NW + j];
    }
    {
        int b = tid >> 2, kk = tid & 3;
        c_lds[b][kk] = 0.f;
        hbase[2 * 32768 + b * 512 + wl * 4 + kk] = 0.f;   // zero h state buffer for t=0
    }
    const float cscale = scale_p[0];

    unsigned target = 1;
    gbar(bar_cnt, bar_gen, target);   // h zeros + setup visible everywhere

    const int b = tid & 63;
    const int wv = tid >> 6;
    const int k0 = __builtin_amdgcn_readfirstlane(wv << 5);  // this wave's k offset within a 128-chunk

    for (int t = 0; t <= TSTEPS + 1; ++t) {
        if (t < TSTEPS) {
            const float* hin = hbase + ((t + 2) % 3) * 32768;
            float* hout = hbase + (t % 3) * 32768;

            // stage x[:, t, :]
            for (int i = tid; i < 1024; i += 256) {
                int bb = i >> 4, cc = i & 15;
                x_lds[bb][cc] = x[(bb * TSTEPS + t) * 16 + cc];
            }

            float acc[16];
#pragma unroll
            for (int r = 0; r < 16; ++r) acc[r] = 0.f;

            for (int c = 0; c < 4; ++c) {
                __syncthreads();
                for (int i = tid; i < 8192; i += 256) {
                    int bb = i >> 7, kl = i & 127;
                    hT[kl][bb] = hin[bb * 512 + c * 128 + kl];
                }
                __syncthreads();
                const float* wrb = wpack_wg + (c * 128 + k0) * 16;
#pragma unroll 4
                for (int kk = 0; kk < 32; ++kk) {
                    float hv = hT[k0 + kk][b];
                    const float4* wq = reinterpret_cast<const float4*>(wrb + (kk << 4));
                    float4 w0 = wq[0], w1 = wq[1], w2 = wq[2], w3 = wq[3];
                    acc[0]  = fmaf(hv, w0.x, acc[0]);  acc[1]  = fmaf(hv, w0.y, acc[1]);
                    acc[2]  = fmaf(hv, w0.z, acc[2]);  acc[3]  = fmaf(hv, w0.w, acc[3]);
                    acc[4]  = fmaf(hv, w1.x, acc[4]);  acc[5]  = fmaf(hv, w1.y, acc[5]);
                    acc[6]  = fmaf(hv, w1.z, acc[6]);  acc[7]  = fmaf(hv, w1.w, acc[7]);
                    acc[8]  = fmaf(hv, w2.x, acc[8]);  acc[9]  = fmaf(hv, w2.y, acc[9]);
                    acc[10] = fmaf(hv, w2.z, acc[10]); acc[11] = fmaf(hv, w2.w, acc[11]);
                    acc[12] = fmaf(hv, w3.x, acc[12]); acc[13] = fmaf(hv, w3.y, acc[13]);
                    acc[14] = fmaf(hv, w3.z, acc[14]); acc[15] = fmaf(hv, w3.w, acc[15]);
                }
            }
            __syncthreads();
#pragma unroll
            for (int r = 0; r < 16; ++r) gparts[r][wv][b] = acc[r];
            __syncthreads();

            // reduce partials, add x-term + bias, LSTM cell, write h slice
            {
                int bb = tid & 63, kk = tid >> 6;
                float gate[4];
#pragma unroll
                for (int q = 0; q < 4; ++q) {
                    int r = kk * 4 + q;
                    float s = gparts[r][0][bb] + gparts[r][1][bb] + gparts[r][2][bb] + gparts[r][3][bb];
                    s += bias_lds[bb][r];
                    for (int j = 0; j < NW; ++j) s = fmaf(x_lds[bb][xoff + j], weff_lds[r][j], s);
                    gate[q] = s;
                }
                float ii = sigm(gate[0]);
                float ff = sigm(gate[1]);
                float gg = tanhf(gate[2]);
                float oo = sigm(gate[3]);
                float cc = fmaf(ff, c_lds[bb][kk], ii * gg);
                c_lds[bb][kk] = cc;
                hout[bb * 512 + wl * 4 + kk] = oo * tanhf(cc);
            }
        }

        // ---- fused command head for time t-1 (cmd WGs 0..63, b = wl) ----
        if (lstm == 0 && wl < 64 && t >= 1 && t <= TSTEPS) {
            int tc = t - 1;
            const float* h = h_c + (tc % 3) * 32768 + wl * 512;
            if (tid < 160) {
                int j = tid >> 4, l = tid & 15;
                const float* wo = w_out_cmd + j * 512;
                float s = 0.f;
                for (int i = 0; i < 32; ++i) { int k = i * 16 + l; s = fmaf(h[k], wo[k], s); }
                s += __shfl_xor(s, 1); s += __shfl_xor(s, 2);
                s += __shfl_xor(s, 4); s += __shfl_xor(s, 8);
                if (l == 0) out[(wl * TSTEPS + tc) * 10 + j] = s + b_out_cmd[j];
            }
        }

        // ---- fused coord head for time t-2 (coord WGs 128..191, b = wl) ----
        if (lstm == 1 && wl < 64 && t >= 2) {
            int tc = t - 2;
            const float* h = h_x + (tc % 3) * 32768 + wl * 512;
            if (tid < 96) {
                int j = tid >> 4, l = tid & 15;
                const float* wo = w_out_coord + j * 522;
                float s = 0.f;
                for (int i = 0; i < 32; ++i) { int k = i * 16 + l; s = fmaf(h[k], wo[k], s); }
                s += __shfl_xor(s, 1); s += __shfl_xor(s, 2);
                s += __shfl_xor(s, 4); s += __shfl_xor(s, 8);
                if (l == 0) {
                    float s2 = s + b_out_coord[j];
                    const float* co = out + (wl * TSTEPS + tc) * 10;
                    for (int i2 = 0; i2 < 10; ++i2) s2 = fmaf(co[i2], wo[512 + i2], s2);
                    out[64 * TSTEPS * 10 + (wl * TSTEPS + tc) * 6 + j] = tanhf(s2 * cscale);
                }
            }
        }

        if (t <= TSTEPS) { ++target; gbar(bar_cnt, bar_gen, target); }
    }
}

// ---------------- host launcher ----------------
extern "C" void kernel_launch(void* const* d_in, const int* in_sizes, int n_in,
                              void* d_out, int out_size, void* d_ws, size_t ws_size,
                              hipStream_t stream)
{
    const float* x            = (const float*)d_in[0];
    const float* context      = (const float*)d_in[1];
    const float* w_cmd_emb    = (const float*)d_in[2];
    const float* b_cmd_emb    = (const float*)d_in[3];
    const float* w_coord_emb  = (const float*)d_in[4];
    const float* b_coord_emb  = (const float*)d_in[5];
    const float* w_ih_cmd     = (const float*)d_in[6];
    const float* w_hh_cmd     = (const float*)d_in[7];
    const float* b_ih_cmd     = (const float*)d_in[8];
    const float* b_hh_cmd     = (const float*)d_in[9];
    const float* w_ih_coord   = (const float*)d_in[10];
    const float* w_hh_coord   = (const float*)d_in[11];
    const float* b_ih_coord   = (const float*)d_in[12];
    const float* b_hh_coord   = (const float*)d_in[13];
    const float* w_out_cmd    = (const float*)d_in[14];
    const float* b_out_cmd    = (const float*)d_in[15];
    const float* w_out_coord  = (const float*)d_in[16];
    const float* b_out_coord  = (const float*)d_in[17];
    const float* scale        = (const float*)d_in[18];

    float* ws  = (float*)d_ws;
    float* out = (float*)d_out;

    float* weff_c  = ws + WS_WEFF_C;
    float* weff_x  = ws + WS_WEFF_X;
    float* biasE_c = ws + WS_BIAS_C;
    float* biasE_x = ws + WS_BIAS_X;
    float* h_c     = ws + WS_H_C;
    float* h_x     = ws + WS_H_X;
    float* wpack   = ws + WS_WPACK;
    unsigned* bar  = (unsigned*)ws;   // WS_BAR

    // zero barrier state (poisoned by harness; must be zero every launch)
    hipMemsetAsync(d_ws, 0, 64 * sizeof(float), stream);

    setup_weff_bias<<<dim3(2048, 2), 256, 0, stream>>>(
        context, w_cmd_emb, b_cmd_emb, w_coord_emb, b_coord_emb,
        w_ih_cmd, b_ih_cmd, b_hh_cmd,
        w_ih_coord, b_ih_coord, b_hh_coord,
        weff_c, weff_x, biasE_c, biasE_x);

    setup_wpack<<<8192, 256, 0, stream>>>(w_hh_cmd, w_hh_coord, wpack);

    void* args[] = {
        (void*)&x, (void*)&wpack,
        (void*)&weff_c, (void*)&weff_x,
        (void*)&biasE_c, (void*)&biasE_x,
        (void*)&h_c, (void*)&h_x,
        (void*)&bar,
        (void*)&w_out_cmd, (void*)&b_out_cmd,
        (void*)&w_out_coord, (void*)&b_out_coord,
        (void*)&scale,
        (void*)&out
    };
    hipLaunchCooperativeKernel((const void*)lstm_main, dim3(NWG_TOT), dim3(256), args, 0, stream);
}

// Round 3
// 10126.434 us; speedup vs baseline: 3.7271x; 3.7271x over previous
//
#include <hip/hip_runtime.h>
#include <hip/hip_bf16.h>
#include <math.h>

#define TSTEPS 1024

typedef __attribute__((ext_vector_type(8))) short short8;
typedef __attribute__((ext_vector_type(4))) float f32x4;

// ---- workspace layout (float units) ----
#define WS_BAR     0                       // 1024 uints (4 KB), zeroed per launch
#define WS_WEFF_C  1024                    // 2048*10
#define WS_WEFF_X  (WS_WEFF_C + 20480)     // 2048*6
#define WS_BIAS_C  (WS_WEFF_X + 12288)     // 64*2048
#define WS_BIAS_X  (WS_BIAS_C + 131072)    // 64*2048
#define WS_HRING   (WS_BIAS_X + 131072)    // shorts: 2*3*65536 -> 196608 floats
#define WS_WPACK   (WS_HRING + 196608)     // shorts: 4194304   -> 2097152 floats

__device__ __forceinline__ float sigm(float v) { return 1.f / (1.f + __expf(-v)); }

// ---------------- setup 1: effective input weights + per-batch bias (validated R1) ----------------
__global__ void setup_weff_bias(const float* __restrict__ ctx,
                                const float* __restrict__ we_c, const float* __restrict__ be_c,
                                const float* __restrict__ we_x, const float* __restrict__ be_x,
                                const float* __restrict__ wih_c, const float* __restrict__ bih_c, const float* __restrict__ bhh_c,
                                const float* __restrict__ wih_x, const float* __restrict__ bih_x, const float* __restrict__ bhh_x,
                                float* __restrict__ weff_c_o, float* __restrict__ weff_x_o,
                                float* __restrict__ biasE_c_o, float* __restrict__ biasE_x_o)
{
    const int g = blockIdx.x;
    const int lstm = blockIdx.y;
    const int tid = threadIdx.x;
    const float* wih  = lstm ? wih_x : wih_c;
    const float* wemb = lstm ? we_x  : we_c;
    const float* bemb = lstm ? be_x  : be_c;
    const int NW = lstm ? 6 : 10;
    float* weff  = lstm ? weff_x_o  : weff_c_o;
    float* biasE = lstm ? biasE_x_o : biasE_c_o;
    const float* wg_ = wih + (size_t)g * 768;

    __shared__ float s_bias0;

    if (tid < NW) {
        float s = 0.f;
        for (int d = 0; d < 512; ++d) s = fmaf(wg_[d], wemb[d * NW + tid], s);
        weff[g * NW + tid] = s;
    }
    if (tid >= 64 && tid < 128) {
        int l = tid - 64;
        float s = 0.f;
        for (int i = 0; i < 8; ++i) { int d = l + i * 64; s = fmaf(wg_[d], bemb[d], s); }
        for (int m = 1; m < 64; m <<= 1) s += __shfl_xor(s, m);
        if (l == 0) s_bias0 = s;
    }
    __syncthreads();
    if (tid >= 128 && tid < 192) {
        int b = tid - 128;
        float s = s_bias0 + (lstm ? (bih_x[g] + bhh_x[g]) : (bih_c[g] + bhh_c[g]));
        const float* cb = ctx + b * 256;
        const float* wc = wg_ + 512;
        for (int c = 0; c < 256; ++c) s = fmaf(wc[c], cb[c], s);
        biasE[b * 2048 + g] = s;
    }
}

// ---------------- setup 2: pack W_hh into MFMA B-frag layout, bf16 hi/lo ----------------
__global__ void setup_wpackF(const float* __restrict__ whh_c, const float* __restrict__ whh_x,
                             short* __restrict__ wpackF)
{
    int idx = blockIdx.x * 256 + threadIdx.x;      // 2^21 total
    int pos = idx & 511;
    int lane = pos >> 3, j = pos & 7;
    int kt4 = (idx >> 9) & 3;
    int q   = (idx >> 11) & 3;
    int wv  = (idx >> 13) & 3;
    int ub  = (idx >> 15) & 31;
    int lstm = (idx >> 20) & 1;
    int g = q * 512 + ub * 16 + (lane & 15);
    int k = wv * 128 + kt4 * 32 + (lane >> 4) * 8 + j;
    const float* whh = lstm ? whh_x : whh_c;
    float v = whh[(size_t)g * 512 + k];
    __hip_bfloat16 hi = __float2bfloat16(v);
    __hip_bfloat16 lo = __float2bfloat16(v - __bfloat162float(hi));
    size_t base = (size_t)(idx >> 9) * 1024 + pos;
    wpackF[base]       = __builtin_bit_cast(short, hi);
    wpackF[base + 512] = __builtin_bit_cast(short, lo);
}

// ---------------- per-LSTM 2-level grid barrier ----------------
__device__ __forceinline__ void gbar(unsigned* bar, int grp, int lstm, unsigned t)
{
    __syncthreads();
    if (threadIdx.x == 0) {
        __builtin_amdgcn_fence(__ATOMIC_RELEASE, "agent");
        unsigned p = __hip_atomic_fetch_add(&bar[grp * 16], 1u, __ATOMIC_RELAXED, __HIP_MEMORY_SCOPE_AGENT);
        if (p == 8u * t - 1u) {
            unsigned p2 = __hip_atomic_fetch_add(&bar[512 + lstm * 16], 1u, __ATOMIC_RELAXED, __HIP_MEMORY_SCOPE_AGENT);
            if (p2 == 16u * t - 1u)
                __hip_atomic_store(&bar[544 + lstm * 16], t, __ATOMIC_RELAXED, __HIP_MEMORY_SCOPE_AGENT);
        }
        while (__hip_atomic_load(&bar[544 + lstm * 16], __ATOMIC_RELAXED, __HIP_MEMORY_SCOPE_AGENT) < t)
            __builtin_amdgcn_s_sleep(1);
        __builtin_amdgcn_fence(__ATOMIC_ACQUIRE, "agent");
    }
    __syncthreads();
}

// ---------------- main persistent kernel ----------------
// 256 WGs x 256 thr. WG = (lstm, ub: 16 units, bt: 16 batches). Waves split k (128 each).
// __launch_bounds__(256,2): cap VGPR<=256 so ANY 2 WGs fit on one CU -> plain launch
// of 256 blocks is always fully co-resident (barrier cannot deadlock).
__global__ __launch_bounds__(256, 2) void lstm_main(
    const float* __restrict__ x,
    const short* __restrict__ wpackF,
    const float* __restrict__ weff_c, const float* __restrict__ weff_x,
    const float* __restrict__ biasE_c, const float* __restrict__ biasE_x,
    short* __restrict__ hring,
    unsigned* __restrict__ bar,
    const float* __restrict__ w_out_cmd, const float* __restrict__ b_out_cmd,
    const float* __restrict__ w_out_coord, const float* __restrict__ b_out_coord,
    float* __restrict__ pre_coord,
    float* __restrict__ out)
{
    __shared__ float lds_gp[4][4][16][17];      // [wv][q][b][u] partial gates
    __shared__ float x_lds[16][10];
    __shared__ float weff_lds[4][16][10];
    __shared__ float w_cmd_lds[32][16][11];     // [k&31][k>>5][j]
    __shared__ float w_coord_lds[32][16][7];

    const int tid = threadIdx.x;
    const int bid = blockIdx.x;
    const int lane = tid & 63;
    const int wv = tid >> 6;
    const int lstm = bid >> 7;
    const int ub = (bid >> 2) & 31;
    const int bt = bid & 3;
    const int u0 = ub * 16, b0 = bt * 16;
    const int NW = lstm ? 6 : 10;
    const int xoff = lstm ? 10 : 0;
    const int u_l = tid & 15, b_l = tid >> 4;
    const int grp = bid >> 3;

    const float* weff  = lstm ? weff_x : weff_c;
    const float* biasE = lstm ? biasE_x : biasE_c;

    const bool head_cmd   = (lstm == 0) && ((bid & 1) == 0);
    const bool head_coord = (lstm == 1) && ((bid & 1) == 0);
    const int hb = (bid & 127) >> 1;
    const int bt2 = hb >> 4, bl2 = hb & 15;

    // ---- one-time: recurrent weight frags into registers (128 VGPRs) ----
    const short* wb = wpackF + (size_t)(((lstm * 32 + ub) * 4 + wv) * 16) * 1024 + lane * 8;
    short8 W[4][4][2];
#pragma unroll
    for (int q = 0; q < 4; ++q)
#pragma unroll
        for (int k4 = 0; k4 < 4; ++k4) {
            W[q][k4][0] = *(const short8*)(wb + (q * 4 + k4) * 1024);
            W[q][k4][1] = *(const short8*)(wb + (q * 4 + k4) * 1024 + 512);
        }

    float biasr[4];
#pragma unroll
    for (int q = 0; q < 4; ++q)
        biasr[q] = biasE[(size_t)(b0 + b_l) * 2048 + q * 512 + u0 + u_l];

    for (int i = tid; i < 64 * NW; i += 256) {
        int r = i / NW, j = i - r * NW;
        weff_lds[r >> 4][r & 15][j] = weff[(size_t)((r >> 4) * 512 + u0 + (r & 15)) * NW + j];
    }
    if (head_cmd) {
        for (int i = tid; i < 5120; i += 256) {
            int k = i / 10, j = i - k * 10;
            w_cmd_lds[k & 31][k >> 5][j] = w_out_cmd[(size_t)j * 512 + k];
        }
    }
    if (head_coord) {
        for (int i = tid; i < 3072; i += 256) {
            int k = i / 6, j = i - k * 6;
            w_coord_lds[k & 31][k >> 5][j] = w_out_coord[(size_t)j * 522 + k];
        }
    }

    float c_reg = 0.f;
    const short* ring_base = hring + (size_t)lstm * 3 * 65536;
    short* ring_base_w = hring + (size_t)lstm * 3 * 65536;

    for (int t = 0; t <= TSTEPS; ++t) {
        if (t < TSTEPS) {
            short8 Ah[4], Al[4];
            if (t > 0) {
                const short* rb = ring_base + ((t + 2) % 3) * 65536 + bt * 16384 + lane * 8;
#pragma unroll
                for (int i = 0; i < 4; ++i) {
                    Ah[i] = *(const short8*)(rb + (wv * 4 + i) * 512);
                    Al[i] = *(const short8*)(rb + 8192 + (wv * 4 + i) * 512);
                }
            }
            if (tid < 16 * NW) {
                int bb = tid / NW, j = tid - bb * NW;
                x_lds[bb][j] = x[(size_t)((b0 + bb) * TSTEPS + t) * 16 + xoff + j];
            }
            f32x4 C[4];
#pragma unroll
            for (int q = 0; q < 4; ++q) { C[q][0] = 0.f; C[q][1] = 0.f; C[q][2] = 0.f; C[q][3] = 0.f; }
            if (t > 0) {
#pragma unroll
                for (int q = 0; q < 4; ++q)
#pragma unroll
                    for (int i = 0; i < 4; ++i) {
                        C[q] = __builtin_amdgcn_mfma_f32_16x16x32_bf16(Ah[i], W[q][i][0], C[q], 0, 0, 0);
                        C[q] = __builtin_amdgcn_mfma_f32_16x16x32_bf16(Al[i], W[q][i][0], C[q], 0, 0, 0);
                        C[q] = __builtin_amdgcn_mfma_f32_16x16x32_bf16(Ah[i], W[q][i][1], C[q], 0, 0, 0);
                    }
            }
#pragma unroll
            for (int q = 0; q < 4; ++q)
#pragma unroll
                for (int i = 0; i < 4; ++i)
                    lds_gp[wv][q][(lane >> 4) * 4 + i][lane & 15] = C[q][i];
            __syncthreads();

            float g4[4];
#pragma unroll
            for (int q = 0; q < 4; ++q) {
                float s = biasr[q];
                s += lds_gp[0][q][b_l][u_l] + lds_gp[1][q][b_l][u_l]
                   + lds_gp[2][q][b_l][u_l] + lds_gp[3][q][b_l][u_l];
                for (int j = 0; j < NW; ++j)
                    s = fmaf(weff_lds[q][u_l][j], x_lds[b_l][j], s);
                g4[q] = s;
            }
            float iv = sigm(g4[0]);
            float fv = sigm(g4[1]);
            float gv = tanhf(g4[2]);
            float ov = sigm(g4[3]);
            c_reg = fmaf(fv, c_reg, iv * gv);
            float hv = ov * tanhf(c_reg);
            __hip_bfloat16 hh = __float2bfloat16(hv);
            __hip_bfloat16 hl = __float2bfloat16(hv - __bfloat162float(hh));
            {
                int ug = u0 + u_l;
                int kt = ug >> 5, ko = ug & 31;
                short* dst = ring_base_w + (t % 3) * 65536 + bt * 16384
                           + kt * 512 + (ko >> 3) * 128 + b_l * 8 + (ko & 7);
                dst[0]    = __builtin_bit_cast(short, hh);
                dst[8192] = __builtin_bit_cast(short, hl);
            }
        }

        if (t >= 1) {
            int tc = t - 1;
            const short* rs = ring_base + (tc % 3) * 65536;
            if (head_cmd && tid < 160) {
                int j = tid >> 4, l = tid & 15;
                const short* p = rs + bt2 * 16384 + l * 512 + bl2 * 8;
                float s = 0.f;
#pragma unroll
                for (int c = 0; c < 4; ++c) {
                    short8 hv8 = *(const short8*)(p + c * 128);
#pragma unroll
                    for (int e = 0; e < 8; ++e) {
                        unsigned u32 = ((unsigned)(unsigned short)hv8[e]) << 16;
                        float hf = __builtin_bit_cast(float, u32);
                        s = fmaf(hf, w_cmd_lds[c * 8 + e][l][j], s);
                    }
                }
                s += __shfl_xor(s, 1); s += __shfl_xor(s, 2);
                s += __shfl_xor(s, 4); s += __shfl_xor(s, 8);
                if (l == 0) out[(size_t)(hb * TSTEPS + tc) * 10 + j] = s + b_out_cmd[j];
            }
            if (head_coord && tid < 96) {
                int j = tid >> 4, l = tid & 15;
                const short* p = rs + bt2 * 16384 + l * 512 + bl2 * 8;
                float s = 0.f;
#pragma unroll
                for (int c = 0; c < 4; ++c) {
                    short8 hv8 = *(const short8*)(p + c * 128);
#pragma unroll
                    for (int e = 0; e < 8; ++e) {
                        unsigned u32 = ((unsigned)(unsigned short)hv8[e]) << 16;
                        float hf = __builtin_bit_cast(float, u32);
                        s = fmaf(hf, w_coord_lds[c * 8 + e][l][j], s);
                    }
                }
                s += __shfl_xor(s, 1); s += __shfl_xor(s, 2);
                s += __shfl_xor(s, 4); s += __shfl_xor(s, 8);
                if (l == 0) pre_coord[(size_t)(hb * TSTEPS + tc) * 6 + j] = s + b_out_coord[j];
            }
        }

        if (t < TSTEPS) gbar(bar, grp, lstm, (unsigned)(t + 1));
    }
}

// ---------------- post: coord output = tanh(scale * (pre + cmd-coupling)), in place ----------------
__global__ void coord_post(const float* __restrict__ w_oc,
                           const float* __restrict__ scale_p, float* __restrict__ out)
{
    int idx = blockIdx.x * 256 + threadIdx.x;
    if (idx >= 64 * TSTEPS * 6) return;
    int j = idx % 6, bt_ = idx / 6;
    float s = out[64 * TSTEPS * 10 + idx];
    const float* cmd = out + (size_t)bt_ * 10;
#pragma unroll
    for (int i = 0; i < 10; ++i) s = fmaf(cmd[i], w_oc[j * 522 + 512 + i], s);
    out[64 * TSTEPS * 10 + idx] = tanhf(s * scale_p[0]);
}

// ---------------- host launcher ----------------
extern "C" void kernel_launch(void* const* d_in, const int* in_sizes, int n_in,
                              void* d_out, int out_size, void* d_ws, size_t ws_size,
                              hipStream_t stream)
{
    const float* x            = (const float*)d_in[0];
    const float* context      = (const float*)d_in[1];
    const float* w_cmd_emb    = (const float*)d_in[2];
    const float* b_cmd_emb    = (const float*)d_in[3];
    const float* w_coord_emb  = (const float*)d_in[4];
    const float* b_coord_emb  = (const float*)d_in[5];
    const float* w_ih_cmd     = (const float*)d_in[6];
    const float* w_hh_cmd     = (const float*)d_in[7];
    const float* b_ih_cmd     = (const float*)d_in[8];
    const float* b_hh_cmd     = (const float*)d_in[9];
    const float* w_ih_coord   = (const float*)d_in[10];
    const float* w_hh_coord   = (const float*)d_in[11];
    const float* b_ih_coord   = (const float*)d_in[12];
    const float* b_hh_coord   = (const float*)d_in[13];
    const float* w_out_cmd    = (const float*)d_in[14];
    const float* b_out_cmd    = (const float*)d_in[15];
    const float* w_out_coord  = (const float*)d_in[16];
    const float* b_out_coord  = (const float*)d_in[17];
    const float* scale        = (const float*)d_in[18];

    float* ws  = (float*)d_ws;
    float* out = (float*)d_out;

    float* weff_c   = ws + WS_WEFF_C;
    float* weff_x   = ws + WS_WEFF_X;
    float* biasE_c  = ws + WS_BIAS_C;
    float* biasE_x  = ws + WS_BIAS_X;
    short* hring    = (short*)(ws + WS_HRING);
    short* wpackF   = (short*)(ws + WS_WPACK);
    unsigned* bar   = (unsigned*)ws;
    float* pre      = out + 64 * TSTEPS * 10;   // coord pre-activations live in out tail

    hipMemsetAsync(d_ws, 0, 4096, stream);

    setup_weff_bias<<<dim3(2048, 2), 256, 0, stream>>>(
        context, w_cmd_emb, b_cmd_emb, w_coord_emb, b_coord_emb,
        w_ih_cmd, b_ih_cmd, b_hh_cmd,
        w_ih_coord, b_ih_coord, b_hh_coord,
        weff_c, weff_x, biasE_c, biasE_x);

    setup_wpackF<<<8192, 256, 0, stream>>>(w_hh_cmd, w_hh_coord, wpackF);

    void* args[] = {
        (void*)&x, (void*)&wpackF,
        (void*)&weff_c, (void*)&weff_x,
        (void*)&biasE_c, (void*)&biasE_x,
        (void*)&hring, (void*)&bar,
        (void*)&w_out_cmd, (void*)&b_out_cmd,
        (void*)&w_out_coord, (void*)&b_out_coord,
        (void*)&pre, (void*)&out
    };
    hipError_t ce = hipLaunchCooperativeKernel((const void*)lstm_main, dim3(256), dim3(256),
                                               args, 0, stream);
    if (ce != hipSuccess) {
        // plain launch: with __launch_bounds__(256,2) any 2 WGs fit per CU, so all
        // 256 blocks are co-resident on 256 CUs regardless of distribution.
        lstm_main<<<dim3(256), dim3(256), 0, stream>>>(
            x, wpackF, weff_c, weff_x, biasE_c, biasE_x, hring, bar,
            w_out_cmd, b_out_cmd, w_out_coord, b_out_coord, pre, out);
    }

    coord_post<<<1536, 256, 0, stream>>>(w_out_coord, scale, out);
}

// Round 4
// 6995.810 us; speedup vs baseline: 5.3949x; 1.4475x over previous
//
#include <hip/hip_runtime.h>
#include <hip/hip_bf16.h>
#include <math.h>

#define TSTEPS 1024

typedef __attribute__((ext_vector_type(8))) short short8;
typedef __attribute__((ext_vector_type(4))) float f32x4;

// ---- workspace layout (float units) ----
#define WS_BAR     0                       // 1024 uints (4 KB), zeroed per launch
#define WS_WEFF_C  1024                    // 2048*10
#define WS_WEFF_X  (WS_WEFF_C + 20480)     // 2048*6
#define WS_BIAS_C  (WS_WEFF_X + 12288)     // 64*2048
#define WS_BIAS_X  (WS_BIAS_C + 131072)    // 64*2048
#define WS_HRING   (WS_BIAS_X + 131072)    // uints: 2*3*32768 = 196608 slots (packed hi|lo)
#define WS_WPACK   (WS_HRING + 196608)     // shorts: 4194304 -> 2097152 floats

__device__ __forceinline__ float sigm(float v) { return 1.f / (1.f + __expf(-v)); }

// ---------------- setup 1: effective input weights + per-batch bias (validated R1/R3) ----------------
__global__ void setup_weff_bias(const float* __restrict__ ctx,
                                const float* __restrict__ we_c, const float* __restrict__ be_c,
                                const float* __restrict__ we_x, const float* __restrict__ be_x,
                                const float* __restrict__ wih_c, const float* __restrict__ bih_c, const float* __restrict__ bhh_c,
                                const float* __restrict__ wih_x, const float* __restrict__ bih_x, const float* __restrict__ bhh_x,
                                float* __restrict__ weff_c_o, float* __restrict__ weff_x_o,
                                float* __restrict__ biasE_c_o, float* __restrict__ biasE_x_o)
{
    const int g = blockIdx.x;
    const int lstm = blockIdx.y;
    const int tid = threadIdx.x;
    const float* wih  = lstm ? wih_x : wih_c;
    const float* wemb = lstm ? we_x  : we_c;
    const float* bemb = lstm ? be_x  : be_c;
    const int NW = lstm ? 6 : 10;
    float* weff  = lstm ? weff_x_o  : weff_c_o;
    float* biasE = lstm ? biasE_x_o : biasE_c_o;
    const float* wg_ = wih + (size_t)g * 768;

    __shared__ float s_bias0;

    if (tid < NW) {
        float s = 0.f;
        for (int d = 0; d < 512; ++d) s = fmaf(wg_[d], wemb[d * NW + tid], s);
        weff[g * NW + tid] = s;
    }
    if (tid >= 64 && tid < 128) {
        int l = tid - 64;
        float s = 0.f;
        for (int i = 0; i < 8; ++i) { int d = l + i * 64; s = fmaf(wg_[d], bemb[d], s); }
        for (int m = 1; m < 64; m <<= 1) s += __shfl_xor(s, m);
        if (l == 0) s_bias0 = s;
    }
    __syncthreads();
    if (tid >= 128 && tid < 192) {
        int b = tid - 128;
        float s = s_bias0 + (lstm ? (bih_x[g] + bhh_x[g]) : (bih_c[g] + bhh_c[g]));
        const float* cb = ctx + b * 256;
        const float* wc = wg_ + 512;
        for (int c = 0; c < 256; ++c) s = fmaf(wc[c], cb[c], s);
        biasE[b * 2048 + g] = s;
    }
}

// ---------------- setup 2: pack W_hh into MFMA B-frag layout, bf16 hi/lo (validated R3) ----------------
__global__ void setup_wpackF(const float* __restrict__ whh_c, const float* __restrict__ whh_x,
                             short* __restrict__ wpackF)
{
    int idx = blockIdx.x * 256 + threadIdx.x;      // 2^21 total
    int pos = idx & 511;
    int lane = pos >> 3, j = pos & 7;
    int kt4 = (idx >> 9) & 3;
    int q   = (idx >> 11) & 3;
    int wv  = (idx >> 13) & 3;
    int ub  = (idx >> 15) & 31;
    int lstm = (idx >> 20) & 1;
    int g = q * 512 + ub * 16 + (lane & 15);
    int k = wv * 128 + kt4 * 32 + (lane >> 4) * 8 + j;
    const float* whh = lstm ? whh_x : whh_c;
    float v = whh[(size_t)g * 512 + k];
    __hip_bfloat16 hi = __float2bfloat16(v);
    __hip_bfloat16 lo = __float2bfloat16(v - __bfloat162float(hi));
    size_t base = (size_t)(idx >> 9) * 1024 + pos;
    wpackF[base]       = __builtin_bit_cast(short, hi);
    wpackF[base + 512] = __builtin_bit_cast(short, lo);
}

// ---------------- per-LSTM 2-level grid barrier: NO cache-wide fences ----------------
// All cross-WG data moves via agent-scope relaxed atomics (coherent-point access),
// so no L2 invalidate/writeback is needed. __syncthreads() before the arrive-add
// drains vmcnt(0): every coherent store of this WG is ACKed at the coherent point.
__device__ __forceinline__ void gbar(unsigned* bar, int grp, int lstm, unsigned t)
{
    __syncthreads();
    if (threadIdx.x == 0) {
        unsigned p = __hip_atomic_fetch_add(&bar[grp * 16], 1u, __ATOMIC_RELAXED, __HIP_MEMORY_SCOPE_AGENT);
        if (p == 8u * t - 1u) {
            unsigned p2 = __hip_atomic_fetch_add(&bar[512 + lstm * 16], 1u, __ATOMIC_RELAXED, __HIP_MEMORY_SCOPE_AGENT);
            if (p2 == 16u * t - 1u)
                __hip_atomic_store(&bar[544 + lstm * 16], t, __ATOMIC_RELAXED, __HIP_MEMORY_SCOPE_AGENT);
        }
        while (__hip_atomic_load(&bar[544 + lstm * 16], __ATOMIC_RELAXED, __HIP_MEMORY_SCOPE_AGENT) < t)
            __builtin_amdgcn_s_sleep(1);
    }
    __syncthreads();
}

// ---------------- main persistent kernel ----------------
// 256 WGs x 256 thr. WG = (lstm, ub: 16 units, bt: 16 batches). Waves split k (128 each).
// h exchanged via packed uint (bf16 hi | lo<<16) ring, accessed ONLY with agent-scope
// relaxed atomics (8B loads / 4B stores) -> cross-XCD coherent without fences.
__global__ __launch_bounds__(256, 2) void lstm_main(
    const float* __restrict__ x,
    const short* __restrict__ wpackF,
    const float* __restrict__ weff_c, const float* __restrict__ weff_x,
    const float* __restrict__ biasE_c, const float* __restrict__ biasE_x,
    unsigned* __restrict__ ring,
    unsigned* __restrict__ bar,
    const float* __restrict__ w_out_cmd, const float* __restrict__ b_out_cmd,
    const float* __restrict__ w_out_coord, const float* __restrict__ b_out_coord,
    float* __restrict__ pre_coord,
    float* __restrict__ out)
{
    __shared__ float lds_gp[4][4][16][17];      // [wv][q][b][u] partial gates
    __shared__ float x_lds[16][10];
    __shared__ float weff_lds[4][16][10];
    __shared__ float w_cmd_lds[32][16][11];     // [k&31][k>>5][j]
    __shared__ float w_coord_lds[32][16][7];

    const int tid = threadIdx.x;
    const int bid = blockIdx.x;
    const int lane = tid & 63;
    const int wv = tid >> 6;
    const int lstm = bid >> 7;
    const int ub = (bid >> 2) & 31;
    const int bt = bid & 3;
    const int u0 = ub * 16, b0 = bt * 16;
    const int NW = lstm ? 6 : 10;
    const int xoff = lstm ? 10 : 0;
    const int u_l = tid & 15, b_l = tid >> 4;
    const int grp = bid >> 3;

    const float* weff  = lstm ? weff_x : weff_c;
    const float* biasE = lstm ? biasE_x : biasE_c;

    const bool head_cmd   = (lstm == 0) && ((bid & 1) == 0);
    const bool head_coord = (lstm == 1) && ((bid & 1) == 0);
    const int hb = (bid & 127) >> 1;
    const int bt2 = hb >> 4, bl2 = hb & 15;

    // ---- one-time: recurrent weight frags into registers/AGPRs ----
    const short* wb = wpackF + (size_t)(((lstm * 32 + ub) * 4 + wv) * 16) * 1024 + lane * 8;
    short8 W[4][4][2];
#pragma unroll
    for (int q = 0; q < 4; ++q)
#pragma unroll
        for (int k4 = 0; k4 < 4; ++k4) {
            W[q][k4][0] = *(const short8*)(wb + (q * 4 + k4) * 1024);
            W[q][k4][1] = *(const short8*)(wb + (q * 4 + k4) * 1024 + 512);
        }

    float biasr[4];
#pragma unroll
    for (int q = 0; q < 4; ++q)
        biasr[q] = biasE[(size_t)(b0 + b_l) * 2048 + q * 512 + u0 + u_l];

    for (int i = tid; i < 64 * NW; i += 256) {
        int r = i / NW, j = i - r * NW;
        weff_lds[r >> 4][r & 15][j] = weff[(size_t)((r >> 4) * 512 + u0 + (r & 15)) * NW + j];
    }
    if (head_cmd) {
        for (int i = tid; i < 5120; i += 256) {
            int k = i / 10, j = i - k * 10;
            w_cmd_lds[k & 31][k >> 5][j] = w_out_cmd[(size_t)j * 512 + k];
        }
    }
    if (head_coord) {
        for (int i = tid; i < 3072; i += 256) {
            int k = i / 6, j = i - k * 6;
            w_coord_lds[k & 31][k >> 5][j] = w_out_coord[(size_t)j * 522 + k];
        }
    }

    float c_reg = 0.f;
    unsigned* ring_l = ring + lstm * 3 * 32768;

    for (int t = 0; t <= TSTEPS; ++t) {
        if (t < TSTEPS) {
            // ---- A-frags: coherent 8B atomic loads of packed h, unpack hi/lo via v_perm ----
            short8 Ah[4], Al[4];
            if (t > 0) {
                const unsigned* rb = ring_l + ((t + 2) % 3) * 32768 + bt * 8192 + lane * 8;
#pragma unroll
                for (int i = 0; i < 4; ++i) {
                    const unsigned long long* p =
                        (const unsigned long long*)(rb + (wv * 4 + i) * 512);
                    unsigned long long q0 = __hip_atomic_load(p + 0, __ATOMIC_RELAXED, __HIP_MEMORY_SCOPE_AGENT);
                    unsigned long long q1 = __hip_atomic_load(p + 1, __ATOMIC_RELAXED, __HIP_MEMORY_SCOPE_AGENT);
                    unsigned long long q2 = __hip_atomic_load(p + 2, __ATOMIC_RELAXED, __HIP_MEMORY_SCOPE_AGENT);
                    unsigned long long q3 = __hip_atomic_load(p + 3, __ATOMIC_RELAXED, __HIP_MEMORY_SCOPE_AGENT);
                    unsigned u0 = (unsigned)q0, u1 = (unsigned)(q0 >> 32);
                    unsigned u2 = (unsigned)q1, u3 = (unsigned)(q1 >> 32);
                    unsigned u4 = (unsigned)q2, u5 = (unsigned)(q2 >> 32);
                    unsigned u6 = (unsigned)q3, u7 = (unsigned)(q3 >> 32);
                    union { unsigned u[4]; short8 s; } ah, al;
                    ah.u[0] = __builtin_amdgcn_perm(u1, u0, 0x05040100u);
                    ah.u[1] = __builtin_amdgcn_perm(u3, u2, 0x05040100u);
                    ah.u[2] = __builtin_amdgcn_perm(u5, u4, 0x05040100u);
                    ah.u[3] = __builtin_amdgcn_perm(u7, u6, 0x05040100u);
                    al.u[0] = __builtin_amdgcn_perm(u1, u0, 0x07060302u);
                    al.u[1] = __builtin_amdgcn_perm(u3, u2, 0x07060302u);
                    al.u[2] = __builtin_amdgcn_perm(u5, u4, 0x07060302u);
                    al.u[3] = __builtin_amdgcn_perm(u7, u6, 0x07060302u);
                    Ah[i] = ah.s;
                    Al[i] = al.s;
                }
            }
            if (tid < 16 * NW) {
                int bb = tid / NW, j = tid - bb * NW;
                x_lds[bb][j] = x[(size_t)((b0 + bb) * TSTEPS + t) * 16 + xoff + j];
            }
            f32x4 C[4];
#pragma unroll
            for (int q = 0; q < 4; ++q) { C[q][0] = 0.f; C[q][1] = 0.f; C[q][2] = 0.f; C[q][3] = 0.f; }
            if (t > 0) {
#pragma unroll
                for (int q = 0; q < 4; ++q)
#pragma unroll
                    for (int i = 0; i < 4; ++i) {
                        C[q] = __builtin_amdgcn_mfma_f32_16x16x32_bf16(Ah[i], W[q][i][0], C[q], 0, 0, 0);
                        C[q] = __builtin_amdgcn_mfma_f32_16x16x32_bf16(Al[i], W[q][i][0], C[q], 0, 0, 0);
                        C[q] = __builtin_amdgcn_mfma_f32_16x16x32_bf16(Ah[i], W[q][i][1], C[q], 0, 0, 0);
                    }
            }
#pragma unroll
            for (int q = 0; q < 4; ++q)
#pragma unroll
                for (int i = 0; i < 4; ++i)
                    lds_gp[wv][q][(lane >> 4) * 4 + i][lane & 15] = C[q][i];
            __syncthreads();

            float g4[4];
#pragma unroll
            for (int q = 0; q < 4; ++q) {
                float s = biasr[q];
                s += lds_gp[0][q][b_l][u_l] + lds_gp[1][q][b_l][u_l]
                   + lds_gp[2][q][b_l][u_l] + lds_gp[3][q][b_l][u_l];
                for (int j = 0; j < NW; ++j)
                    s = fmaf(weff_lds[q][u_l][j], x_lds[b_l][j], s);
                g4[q] = s;
            }
            float iv = sigm(g4[0]);
            float fv = sigm(g4[1]);
            float gv = tanhf(g4[2]);
            float ov = sigm(g4[3]);
            c_reg = fmaf(fv, c_reg, iv * gv);
            float hv = ov * tanhf(c_reg);
            __hip_bfloat16 hh = __float2bfloat16(hv);
            __hip_bfloat16 hl = __float2bfloat16(hv - __bfloat162float(hh));
            {
                int ug = u0 + u_l;
                int kt = ug >> 5, ko = ug & 31;
                unsigned pack = (unsigned)(unsigned short)__builtin_bit_cast(short, hh)
                              | ((unsigned)(unsigned short)__builtin_bit_cast(short, hl) << 16);
                unsigned idx = (unsigned)((t % 3) * 32768 + bt * 8192 + kt * 512
                             + ((ko >> 3) * 16 + b_l) * 8 + (ko & 7));
                __hip_atomic_store(&ring_l[idx], pack, __ATOMIC_RELAXED, __HIP_MEMORY_SCOPE_AGENT);
            }
        }

        // ---- fused heads for tc = t-1 (hi-only from packed ring, coherent loads) ----
        if (t >= 1) {
            int tc = t - 1;
            const unsigned* rs = ring_l + (tc % 3) * 32768 + bt2 * 8192;
            if (head_cmd && tid < 160) {
                int j = tid >> 4, l = tid & 15;
                float s = 0.f;
#pragma unroll
                for (int c = 0; c < 4; ++c) {
                    const unsigned long long* hp =
                        (const unsigned long long*)(rs + l * 512 + (c * 16 + bl2) * 8);
                    unsigned long long a0 = __hip_atomic_load(hp + 0, __ATOMIC_RELAXED, __HIP_MEMORY_SCOPE_AGENT);
                    unsigned long long a1 = __hip_atomic_load(hp + 1, __ATOMIC_RELAXED, __HIP_MEMORY_SCOPE_AGENT);
                    unsigned long long a2 = __hip_atomic_load(hp + 2, __ATOMIC_RELAXED, __HIP_MEMORY_SCOPE_AGENT);
                    unsigned long long a3 = __hip_atomic_load(hp + 3, __ATOMIC_RELAXED, __HIP_MEMORY_SCOPE_AGENT);
                    unsigned uu[8] = { (unsigned)a0, (unsigned)(a0 >> 32),
                                       (unsigned)a1, (unsigned)(a1 >> 32),
                                       (unsigned)a2, (unsigned)(a2 >> 32),
                                       (unsigned)a3, (unsigned)(a3 >> 32) };
#pragma unroll
                    for (int e = 0; e < 8; ++e) {
                        float hf = __builtin_bit_cast(float, uu[e] << 16);
                        s = fmaf(hf, w_cmd_lds[c * 8 + e][l][j], s);
                    }
                }
                s += __shfl_xor(s, 1); s += __shfl_xor(s, 2);
                s += __shfl_xor(s, 4); s += __shfl_xor(s, 8);
                if (l == 0) out[(size_t)(hb * TSTEPS + tc) * 10 + j] = s + b_out_cmd[j];
            }
            if (head_coord && tid < 96) {
                int j = tid >> 4, l = tid & 15;
                float s = 0.f;
#pragma unroll
                for (int c = 0; c < 4; ++c) {
                    const unsigned long long* hp =
                        (const unsigned long long*)(rs + l * 512 + (c * 16 + bl2) * 8);
                    unsigned long long a0 = __hip_atomic_load(hp + 0, __ATOMIC_RELAXED, __HIP_MEMORY_SCOPE_AGENT);
                    unsigned long long a1 = __hip_atomic_load(hp + 1, __ATOMIC_RELAXED, __HIP_MEMORY_SCOPE_AGENT);
                    unsigned long long a2 = __hip_atomic_load(hp + 2, __ATOMIC_RELAXED, __HIP_MEMORY_SCOPE_AGENT);
                    unsigned long long a3 = __hip_atomic_load(hp + 3, __ATOMIC_RELAXED, __HIP_MEMORY_SCOPE_AGENT);
                    unsigned uu[8] = { (unsigned)a0, (unsigned)(a0 >> 32),
                                       (unsigned)a1, (unsigned)(a1 >> 32),
                                       (unsigned)a2, (unsigned)(a2 >> 32),
                                       (unsigned)a3, (unsigned)(a3 >> 32) };
#pragma unroll
                    for (int e = 0; e < 8; ++e) {
                        float hf = __builtin_bit_cast(float, uu[e] << 16);
                        s = fmaf(hf, w_coord_lds[c * 8 + e][l][j], s);
                    }
                }
                s += __shfl_xor(s, 1); s += __shfl_xor(s, 2);
                s += __shfl_xor(s, 4); s += __shfl_xor(s, 8);
                if (l == 0) pre_coord[(size_t)(hb * TSTEPS + tc) * 6 + j] = s + b_out_coord[j];
            }
        }

        if (t < TSTEPS) gbar(bar, grp, lstm, (unsigned)(t + 1));
    }
}

// ---------------- post: coord output = tanh(scale * (pre + cmd-coupling)), in place ----------------
__global__ void coord_post(const float* __restrict__ w_oc,
                           const float* __restrict__ scale_p, float* __restrict__ out)
{
    int idx = blockIdx.x * 256 + threadIdx.x;
    if (idx >= 64 * TSTEPS * 6) return;
    int j = idx % 6, bt_ = idx / 6;
    float s = out[64 * TSTEPS * 10 + idx];
    const float* cmd = out + (size_t)bt_ * 10;
#pragma unroll
    for (int i = 0; i < 10; ++i) s = fmaf(cmd[i], w_oc[j * 522 + 512 + i], s);
    out[64 * TSTEPS * 10 + idx] = tanhf(s * scale_p[0]);
}

// ---------------- host launcher ----------------
extern "C" void kernel_launch(void* const* d_in, const int* in_sizes, int n_in,
                              void* d_out, int out_size, void* d_ws, size_t ws_size,
                              hipStream_t stream)
{
    const float* x            = (const float*)d_in[0];
    const float* context      = (const float*)d_in[1];
    const float* w_cmd_emb    = (const float*)d_in[2];
    const float* b_cmd_emb    = (const float*)d_in[3];
    const float* w_coord_emb  = (const float*)d_in[4];
    const float* b_coord_emb  = (const float*)d_in[5];
    const float* w_ih_cmd     = (const float*)d_in[6];
    const float* w_hh_cmd     = (const float*)d_in[7];
    const float* b_ih_cmd     = (const float*)d_in[8];
    const float* b_hh_cmd     = (const float*)d_in[9];
    const float* w_ih_coord   = (const float*)d_in[10];
    const float* w_hh_coord   = (const float*)d_in[11];
    const float* b_ih_coord   = (const float*)d_in[12];
    const float* b_hh_coord   = (const float*)d_in[13];
    const float* w_out_cmd    = (const float*)d_in[14];
    const float* b_out_cmd    = (const float*)d_in[15];
    const float* w_out_coord  = (const float*)d_in[16];
    const float* b_out_coord  = (const float*)d_in[17];
    const float* scale        = (const float*)d_in[18];

    float* ws  = (float*)d_ws;
    float* out = (float*)d_out;

    float* weff_c   = ws + WS_WEFF_C;
    float* weff_x   = ws + WS_WEFF_X;
    float* biasE_c  = ws + WS_BIAS_C;
    float* biasE_x  = ws + WS_BIAS_X;
    unsigned* ring  = (unsigned*)(ws + WS_HRING);
    short* wpackF   = (short*)(ws + WS_WPACK);
    unsigned* bar   = (unsigned*)ws;
    float* pre      = out + 64 * TSTEPS * 10;   // coord pre-activations live in out tail

    hipMemsetAsync(d_ws, 0, 4096, stream);

    setup_weff_bias<<<dim3(2048, 2), 256, 0, stream>>>(
        context, w_cmd_emb, b_cmd_emb, w_coord_emb, b_coord_emb,
        w_ih_cmd, b_ih_cmd, b_hh_cmd,
        w_ih_coord, b_ih_coord, b_hh_coord,
        weff_c, weff_x, biasE_c, biasE_x);

    setup_wpackF<<<8192, 256, 0, stream>>>(w_hh_cmd, w_hh_coord, wpackF);

    void* args[] = {
        (void*)&x, (void*)&wpackF,
        (void*)&weff_c, (void*)&weff_x,
        (void*)&biasE_c, (void*)&biasE_x,
        (void*)&ring, (void*)&bar,
        (void*)&w_out_cmd, (void*)&b_out_cmd,
        (void*)&w_out_coord, (void*)&b_out_coord,
        (void*)&pre, (void*)&out
    };
    hipError_t ce = hipLaunchCooperativeKernel((const void*)lstm_main, dim3(256), dim3(256),
                                               args, 0, stream);
    if (ce != hipSuccess) {
        // plain launch: with __launch_bounds__(256,2) any 2 WGs fit per CU, so all
        // 256 blocks are co-resident on 256 CUs regardless of distribution.
        lstm_main<<<dim3(256), dim3(256), 0, stream>>>(
            x, wpackF, weff_c, weff_x, biasE_c, biasE_x, ring, bar,
            w_out_cmd, b_out_cmd, w_out_coord, b_out_coord, pre, out);
    }

    coord_post<<<1536, 256, 0, stream>>>(w_out_coord, scale, out);
}

// Round 5
// 5170.293 us; speedup vs baseline: 7.2998x; 1.3531x over previous
//
#include <hip/hip_runtime.h>
#include <hip/hip_bf16.h>
#include <math.h>

#define TSTEPS 1024

typedef __attribute__((ext_vector_type(8))) short short8;
typedef __attribute__((ext_vector_type(4))) float f32x4;

// ---- workspace layout (float units) ----
#define WS_BAR     0                       // 1024 uints (4 KB) flags, zeroed per launch
#define WS_WEFF_C  1024                    // 2048*10
#define WS_WEFF_X  (WS_WEFF_C + 20480)     // 2048*6
#define WS_BIAS_C  (WS_WEFF_X + 12288)     // 64*2048
#define WS_BIAS_X  (WS_BIAS_C + 131072)    // 64*2048
#define WS_HRING   (WS_BIAS_X + 131072)    // uints: 8 islands * 4 slots * 8192 = 262144
#define WS_WPACK   (WS_HRING + 262144)     // shorts: 4194304 -> 2097152 floats

__device__ __forceinline__ float sigm(float v) { return 1.f / (1.f + __expf(-v)); }

// ---------------- setup 1: effective input weights + per-batch bias (validated R1/R3/R4) ----------------
__global__ void setup_weff_bias(const float* __restrict__ ctx,
                                const float* __restrict__ we_c, const float* __restrict__ be_c,
                                const float* __restrict__ we_x, const float* __restrict__ be_x,
                                const float* __restrict__ wih_c, const float* __restrict__ bih_c, const float* __restrict__ bhh_c,
                                const float* __restrict__ wih_x, const float* __restrict__ bih_x, const float* __restrict__ bhh_x,
                                float* __restrict__ weff_c_o, float* __restrict__ weff_x_o,
                                float* __restrict__ biasE_c_o, float* __restrict__ biasE_x_o)
{
    const int g = blockIdx.x;
    const int lstm = blockIdx.y;
    const int tid = threadIdx.x;
    const float* wih  = lstm ? wih_x : wih_c;
    const float* wemb = lstm ? we_x  : we_c;
    const float* bemb = lstm ? be_x  : be_c;
    const int NW = lstm ? 6 : 10;
    float* weff  = lstm ? weff_x_o  : weff_c_o;
    float* biasE = lstm ? biasE_x_o : biasE_c_o;
    const float* wg_ = wih + (size_t)g * 768;

    __shared__ float s_bias0;

    if (tid < NW) {
        float s = 0.f;
        for (int d = 0; d < 512; ++d) s = fmaf(wg_[d], wemb[d * NW + tid], s);
        weff[g * NW + tid] = s;
    }
    if (tid >= 64 && tid < 128) {
        int l = tid - 64;
        float s = 0.f;
        for (int i = 0; i < 8; ++i) { int d = l + i * 64; s = fmaf(wg_[d], bemb[d], s); }
        for (int m = 1; m < 64; m <<= 1) s += __shfl_xor(s, m);
        if (l == 0) s_bias0 = s;
    }
    __syncthreads();
    if (tid >= 128 && tid < 192) {
        int b = tid - 128;
        float s = s_bias0 + (lstm ? (bih_x[g] + bhh_x[g]) : (bih_c[g] + bhh_c[g]));
        const float* cb = ctx + b * 256;
        const float* wc = wg_ + 512;
        for (int c = 0; c < 256; ++c) s = fmaf(wc[c], cb[c], s);
        biasE[b * 2048 + g] = s;
    }
}

// ---------------- setup 2: pack W_hh into MFMA B-frag layout, bf16 hi/lo (validated R3/R4) ----------------
__global__ void setup_wpackF(const float* __restrict__ whh_c, const float* __restrict__ whh_x,
                             short* __restrict__ wpackF)
{
    int idx = blockIdx.x * 256 + threadIdx.x;      // 2^21 total
    int pos = idx & 511;
    int lane = pos >> 3, j = pos & 7;
    int kt4 = (idx >> 9) & 3;
    int q   = (idx >> 11) & 3;
    int wv  = (idx >> 13) & 3;
    int ub  = (idx >> 15) & 31;
    int lstm = (idx >> 20) & 1;
    int g = q * 512 + ub * 16 + (lane & 15);
    int k = wv * 128 + kt4 * 32 + (lane >> 4) * 8 + j;
    const float* whh = lstm ? whh_x : whh_c;
    float v = whh[(size_t)g * 512 + k];
    __hip_bfloat16 hi = __float2bfloat16(v);
    __hip_bfloat16 lo = __float2bfloat16(v - __bfloat162float(hi));
    size_t base = (size_t)(idx >> 9) * 1024 + pos;
    wpackF[base]       = __builtin_bit_cast(short, hi);
    wpackF[base + 512] = __builtin_bit_cast(short, lo);
}

// ---------------- main persistent kernel: 8 independent islands of 32 WGs ----------------
// Island = (lstm, bt): 32 WGs (one per ub) own a 16-batch slice end-to-end.
// Sync: per-island 32-flag line (epoch-numbered, no reset), depth-4 h ring.
// No grid barrier. h moves via agent-scope relaxed atomics (write-through, validated R4).
__global__ __launch_bounds__(256, 2) void lstm_main(
    const float* __restrict__ x,
    const short* __restrict__ wpackF,
    const float* __restrict__ weff_c, const float* __restrict__ weff_x,
    const float* __restrict__ biasE_c, const float* __restrict__ biasE_x,
    unsigned* __restrict__ ring,
    unsigned* __restrict__ bar,
    const float* __restrict__ w_out_cmd, const float* __restrict__ b_out_cmd,
    const float* __restrict__ w_out_coord, const float* __restrict__ b_out_coord,
    float* __restrict__ pre_coord,
    float* __restrict__ out)
{
    __shared__ float lds_gp[4][4][16][17];      // [wv][q][b][u] partial gates
    __shared__ float x_lds[16][10];
    __shared__ float weff_lds[4][16][10];
    __shared__ float w_cmd_lds[32][16][11];     // [k&31][k>>5][j]
    __shared__ float w_coord_lds[32][16][7];

    const int tid = threadIdx.x;
    const int bid = blockIdx.x;
    const int lane = tid & 63;
    const int wv = tid >> 6;
    const int lstm = bid >> 7;
    const int ub = (bid >> 2) & 31;
    const int bt = bid & 3;
    const int island = lstm * 4 + bt;
    const int u0 = ub * 16, b0 = bt * 16;
    const int NW = lstm ? 6 : 10;
    const int xoff = lstm ? 10 : 0;
    const int u_l = tid & 15, b_l = tid >> 4;

    const float* weff  = lstm ? weff_x : weff_c;
    const float* biasE = lstm ? biasE_x : biasE_c;

    unsigned* flags = bar + island * 64;            // 32 flags, one 128B line
    unsigned* ring_isl = ring + island * 4 * 8192;  // 4 slots x 8192 uints

    const bool is_head = (ub < 16);                 // handles batch b0+ub of its lstm
    const int hbatch = b0 + ub;

    // ---- one-time: recurrent weight frags into registers/AGPRs ----
    const short* wb = wpackF + (size_t)(((lstm * 32 + ub) * 4 + wv) * 16) * 1024 + lane * 8;
    short8 W[4][4][2];
#pragma unroll
    for (int q = 0; q < 4; ++q)
#pragma unroll
        for (int k4 = 0; k4 < 4; ++k4) {
            W[q][k4][0] = *(const short8*)(wb + (q * 4 + k4) * 1024);
            W[q][k4][1] = *(const short8*)(wb + (q * 4 + k4) * 1024 + 512);
        }

    float biasr[4];
#pragma unroll
    for (int q = 0; q < 4; ++q)
        biasr[q] = biasE[(size_t)(b0 + b_l) * 2048 + q * 512 + u0 + u_l];

    for (int i = tid; i < 64 * NW; i += 256) {
        int r = i / NW, j = i - r * NW;
        weff_lds[r >> 4][r & 15][j] = weff[(size_t)((r >> 4) * 512 + u0 + (r & 15)) * NW + j];
    }
    if (lstm == 0 && is_head) {
        for (int i = tid; i < 5120; i += 256) {
            int k = i / 10, j = i - k * 10;
            w_cmd_lds[k & 31][k >> 5][j] = w_out_cmd[(size_t)j * 512 + k];
        }
    }
    if (lstm == 1 && is_head) {
        for (int i = tid; i < 3072; i += 256) {
            int k = i / 6, j = i - k * 6;
            w_coord_lds[k & 31][k >> 5][j] = w_out_coord[(size_t)j * 522 + k];
        }
    }

    float c_reg = 0.f;

    for (int t = 0; t <= TSTEPS; ++t) {
        // ---- x prefetch for step t (static input: issue before the poll) ----
        float xv = 0.f;
        int xb = 0, xj = 0;
        const bool hasx = (t < TSTEPS) && (tid < 16 * NW);
        if (hasx) {
            xb = tid / NW; xj = tid - xb * NW;
            xv = x[(size_t)((b0 + xb) * TSTEPS + t) * 16 + xoff + xj];
        }

        // ---- poll island flags >= t : h_{t-1} of all 32 producers is visible ----
        if (t > 0) {
            if (wv == 0) {
                const unsigned tgt = (unsigned)t;
                const int fl = lane & 31;
                while (true) {
                    unsigned v = __hip_atomic_load(&flags[fl], __ATOMIC_RELAXED, __HIP_MEMORY_SCOPE_AGENT);
                    if (__all((int)(v >= tgt))) break;
                }
            }
            __syncthreads();
            asm volatile("" ::: "memory");
            __builtin_amdgcn_sched_barrier(0);
        }

        if (t < TSTEPS) {
            // ---- A-frags: coherent 8B atomic loads of packed h_{t-1}, unpack hi/lo ----
            short8 Ah[4], Al[4];
            if (t > 0) {
                const unsigned* rb = ring_isl + ((t + 3) & 3) * 8192 + lane * 8;
#pragma unroll
                for (int i = 0; i < 4; ++i) {
                    const unsigned long long* p =
                        (const unsigned long long*)(rb + (wv * 4 + i) * 512);
                    unsigned long long q0 = __hip_atomic_load(p + 0, __ATOMIC_RELAXED, __HIP_MEMORY_SCOPE_AGENT);
                    unsigned long long q1 = __hip_atomic_load(p + 1, __ATOMIC_RELAXED, __HIP_MEMORY_SCOPE_AGENT);
                    unsigned long long q2 = __hip_atomic_load(p + 2, __ATOMIC_RELAXED, __HIP_MEMORY_SCOPE_AGENT);
                    unsigned long long q3 = __hip_atomic_load(p + 3, __ATOMIC_RELAXED, __HIP_MEMORY_SCOPE_AGENT);
                    unsigned u0_ = (unsigned)q0, u1_ = (unsigned)(q0 >> 32);
                    unsigned u2_ = (unsigned)q1, u3_ = (unsigned)(q1 >> 32);
                    unsigned u4_ = (unsigned)q2, u5_ = (unsigned)(q2 >> 32);
                    unsigned u6_ = (unsigned)q3, u7_ = (unsigned)(q3 >> 32);
                    union { unsigned u[4]; short8 s; } ah, al;
                    ah.u[0] = __builtin_amdgcn_perm(u1_, u0_, 0x05040100u);
                    ah.u[1] = __builtin_amdgcn_perm(u3_, u2_, 0x05040100u);
                    ah.u[2] = __builtin_amdgcn_perm(u5_, u4_, 0x05040100u);
                    ah.u[3] = __builtin_amdgcn_perm(u7_, u6_, 0x05040100u);
                    al.u[0] = __builtin_amdgcn_perm(u1_, u0_, 0x07060302u);
                    al.u[1] = __builtin_amdgcn_perm(u3_, u2_, 0x07060302u);
                    al.u[2] = __builtin_amdgcn_perm(u5_, u4_, 0x07060302u);
                    al.u[3] = __builtin_amdgcn_perm(u7_, u6_, 0x07060302u);
                    Ah[i] = ah.s;
                    Al[i] = al.s;
                }
            }
            f32x4 C[4];
#pragma unroll
            for (int q = 0; q < 4; ++q) { C[q][0] = 0.f; C[q][1] = 0.f; C[q][2] = 0.f; C[q][3] = 0.f; }
            if (t > 0) {
#pragma unroll
                for (int q = 0; q < 4; ++q)
#pragma unroll
                    for (int i = 0; i < 4; ++i) {
                        C[q] = __builtin_amdgcn_mfma_f32_16x16x32_bf16(Ah[i], W[q][i][0], C[q], 0, 0, 0);
                        C[q] = __builtin_amdgcn_mfma_f32_16x16x32_bf16(Al[i], W[q][i][0], C[q], 0, 0, 0);
                        C[q] = __builtin_amdgcn_mfma_f32_16x16x32_bf16(Ah[i], W[q][i][1], C[q], 0, 0, 0);
                    }
            }
            if (hasx) x_lds[xb][xj] = xv;
#pragma unroll
            for (int q = 0; q < 4; ++q)
#pragma unroll
                for (int i = 0; i < 4; ++i)
                    lds_gp[wv][q][(lane >> 4) * 4 + i][lane & 15] = C[q][i];
            __syncthreads();

            float g4[4];
#pragma unroll
            for (int q = 0; q < 4; ++q) {
                float s = biasr[q];
                s += lds_gp[0][q][b_l][u_l] + lds_gp[1][q][b_l][u_l]
                   + lds_gp[2][q][b_l][u_l] + lds_gp[3][q][b_l][u_l];
                for (int j = 0; j < NW; ++j)
                    s = fmaf(weff_lds[q][u_l][j], x_lds[b_l][j], s);
                g4[q] = s;
            }
            float iv = sigm(g4[0]);
            float fv = sigm(g4[1]);
            float gv = tanhf(g4[2]);
            float ov = sigm(g4[3]);
            c_reg = fmaf(fv, c_reg, iv * gv);
            float hv = ov * tanhf(c_reg);
            __hip_bfloat16 hh = __float2bfloat16(hv);
            __hip_bfloat16 hl = __float2bfloat16(hv - __bfloat162float(hh));
            {
                int ug = u0 + u_l;
                int kt = ug >> 5, ko = ug & 31;
                unsigned pack = (unsigned)(unsigned short)__builtin_bit_cast(short, hh)
                              | ((unsigned)(unsigned short)__builtin_bit_cast(short, hl) << 16);
                unsigned idx = (unsigned)((t & 3) * 8192 + kt * 512
                             + ((ko >> 3) * 16 + b_l) * 8 + (ko & 7));
                __hip_atomic_store(&ring_isl[idx], pack, __ATOMIC_RELAXED, __HIP_MEMORY_SCOPE_AGENT);
            }
            // drain all waves' ring stores (syncthreads waits vmcnt(0) per wave), then publish
            __syncthreads();
            if (tid == 0)
                __hip_atomic_store(&flags[ub], (unsigned)(t + 1), __ATOMIC_RELAXED, __HIP_MEMORY_SCOPE_AGENT);
        }

        // ---- fused heads for tc = t-1 (island-local read, gated by this epoch's poll) ----
        if (t >= 1 && is_head) {
            const int tc = t - 1;
            const unsigned* rs = ring_isl + (tc & 3) * 8192;
            if (lstm == 0 && tid < 160) {
                int j = tid >> 4, l = tid & 15;
                float s = 0.f;
#pragma unroll
                for (int c = 0; c < 4; ++c) {
                    const unsigned long long* hp =
                        (const unsigned long long*)(rs + l * 512 + (c * 16 + ub) * 8);
                    unsigned long long a0 = __hip_atomic_load(hp + 0, __ATOMIC_RELAXED, __HIP_MEMORY_SCOPE_AGENT);
                    unsigned long long a1 = __hip_atomic_load(hp + 1, __ATOMIC_RELAXED, __HIP_MEMORY_SCOPE_AGENT);
                    unsigned long long a2 = __hip_atomic_load(hp + 2, __ATOMIC_RELAXED, __HIP_MEMORY_SCOPE_AGENT);
                    unsigned long long a3 = __hip_atomic_load(hp + 3, __ATOMIC_RELAXED, __HIP_MEMORY_SCOPE_AGENT);
                    unsigned uu[8] = { (unsigned)a0, (unsigned)(a0 >> 32),
                                       (unsigned)a1, (unsigned)(a1 >> 32),
                                       (unsigned)a2, (unsigned)(a2 >> 32),
                                       (unsigned)a3, (unsigned)(a3 >> 32) };
#pragma unroll
                    for (int e = 0; e < 8; ++e) {
                        float hf = __builtin_bit_cast(float, uu[e] << 16);
                        s = fmaf(hf, w_cmd_lds[c * 8 + e][l][j], s);
                    }
                }
                s += __shfl_xor(s, 1); s += __shfl_xor(s, 2);
                s += __shfl_xor(s, 4); s += __shfl_xor(s, 8);
                if (l == 0) out[(size_t)(hbatch * TSTEPS + tc) * 10 + j] = s + b_out_cmd[j];
            }
            if (lstm == 1 && tid < 96) {
                int j = tid >> 4, l = tid & 15;
                float s = 0.f;
#pragma unroll
                for (int c = 0; c < 4; ++c) {
                    const unsigned long long* hp =
                        (const unsigned long long*)(rs + l * 512 + (c * 16 + ub) * 8);
                    unsigned long long a0 = __hip_atomic_load(hp + 0, __ATOMIC_RELAXED, __HIP_MEMORY_SCOPE_AGENT);
                    unsigned long long a1 = __hip_atomic_load(hp + 1, __ATOMIC_RELAXED, __HIP_MEMORY_SCOPE_AGENT);
                    unsigned long long a2 = __hip_atomic_load(hp + 2, __ATOMIC_RELAXED, __HIP_MEMORY_SCOPE_AGENT);
                    unsigned long long a3 = __hip_atomic_load(hp + 3, __ATOMIC_RELAXED, __HIP_MEMORY_SCOPE_AGENT);
                    unsigned uu[8] = { (unsigned)a0, (unsigned)(a0 >> 32),
                                       (unsigned)a1, (unsigned)(a1 >> 32),
                                       (unsigned)a2, (unsigned)(a2 >> 32),
                                       (unsigned)a3, (unsigned)(a3 >> 32) };
#pragma unroll
                    for (int e = 0; e < 8; ++e) {
                        float hf = __builtin_bit_cast(float, uu[e] << 16);
                        s = fmaf(hf, w_coord_lds[c * 8 + e][l][j], s);
                    }
                }
                s += __shfl_xor(s, 1); s += __shfl_xor(s, 2);
                s += __shfl_xor(s, 4); s += __shfl_xor(s, 8);
                if (l == 0) pre_coord[(size_t)(hbatch * TSTEPS + tc) * 6 + j] = s + b_out_coord[j];
            }
        }
    }
}

// ---------------- post: coord output = tanh(scale * (pre + cmd-coupling)), in place ----------------
__global__ void coord_post(const float* __restrict__ w_oc,
                           const float* __restrict__ scale_p, float* __restrict__ out)
{
    int idx = blockIdx.x * 256 + threadIdx.x;
    if (idx >= 64 * TSTEPS * 6) return;
    int j = idx % 6, bt_ = idx / 6;
    float s = out[64 * TSTEPS * 10 + idx];
    const float* cmd = out + (size_t)bt_ * 10;
#pragma unroll
    for (int i = 0; i < 10; ++i) s = fmaf(cmd[i], w_oc[j * 522 + 512 + i], s);
    out[64 * TSTEPS * 10 + idx] = tanhf(s * scale_p[0]);
}

// ---------------- host launcher ----------------
extern "C" void kernel_launch(void* const* d_in, const int* in_sizes, int n_in,
                              void* d_out, int out_size, void* d_ws, size_t ws_size,
                              hipStream_t stream)
{
    const float* x            = (const float*)d_in[0];
    const float* context      = (const float*)d_in[1];
    const float* w_cmd_emb    = (const float*)d_in[2];
    const float* b_cmd_emb    = (const float*)d_in[3];
    const float* w_coord_emb  = (const float*)d_in[4];
    const float* b_coord_emb  = (const float*)d_in[5];
    const float* w_ih_cmd     = (const float*)d_in[6];
    const float* w_hh_cmd     = (const float*)d_in[7];
    const float* b_ih_cmd     = (const float*)d_in[8];
    const float* b_hh_cmd     = (const float*)d_in[9];
    const float* w_ih_coord   = (const float*)d_in[10];
    const float* w_hh_coord   = (const float*)d_in[11];
    const float* b_ih_coord   = (const float*)d_in[12];
    const float* b_hh_coord   = (const float*)d_in[13];
    const float* w_out_cmd    = (const float*)d_in[14];
    const float* b_out_cmd    = (const float*)d_in[15];
    const float* w_out_coord  = (const float*)d_in[16];
    const float* b_out_coord  = (const float*)d_in[17];
    const float* scale        = (const float*)d_in[18];

    float* ws  = (float*)d_ws;
    float* out = (float*)d_out;

    float* weff_c   = ws + WS_WEFF_C;
    float* weff_x   = ws + WS_WEFF_X;
    float* biasE_c  = ws + WS_BIAS_C;
    float* biasE_x  = ws + WS_BIAS_X;
    unsigned* ring  = (unsigned*)(ws + WS_HRING);
    short* wpackF   = (short*)(ws + WS_WPACK);
    unsigned* bar   = (unsigned*)ws;
    float* pre      = out + 64 * TSTEPS * 10;   // coord pre-activations live in out tail

    hipMemsetAsync(d_ws, 0, 4096, stream);      // zero flags every launch

    setup_weff_bias<<<dim3(2048, 2), 256, 0, stream>>>(
        context, w_cmd_emb, b_cmd_emb, w_coord_emb, b_coord_emb,
        w_ih_cmd, b_ih_cmd, b_hh_cmd,
        w_ih_coord, b_ih_coord, b_hh_coord,
        weff_c, weff_x, biasE_c, biasE_x);

    setup_wpackF<<<8192, 256, 0, stream>>>(w_hh_cmd, w_hh_coord, wpackF);

    void* args[] = {
        (void*)&x, (void*)&wpackF,
        (void*)&weff_c, (void*)&weff_x,
        (void*)&biasE_c, (void*)&biasE_x,
        (void*)&ring, (void*)&bar,
        (void*)&w_out_cmd, (void*)&b_out_cmd,
        (void*)&w_out_coord, (void*)&b_out_coord,
        (void*)&pre, (void*)&out
    };
    hipError_t ce = hipLaunchCooperativeKernel((const void*)lstm_main, dim3(256), dim3(256),
                                               args, 0, stream);
    if (ce != hipSuccess) {
        // plain launch: with __launch_bounds__(256,2) any 2 WGs fit per CU, so all
        // 256 blocks are co-resident on 256 CUs regardless of distribution.
        lstm_main<<<dim3(256), dim3(256), 0, stream>>>(
            x, wpackF, weff_c, weff_x, biasE_c, biasE_x, ring, bar,
            w_out_cmd, b_out_cmd, w_out_coord, b_out_coord, pre, out);
    }

    coord_post<<<1536, 256, 0, stream>>>(w_out_coord, scale, out);
}

// Round 7
// 4790.643 us; speedup vs baseline: 7.8782x; 1.0792x over previous
//
#include <hip/hip_runtime.h>
#include <hip/hip_bf16.h>
#include <math.h>

#define TSTEPS 1024

typedef __attribute__((ext_vector_type(8))) short short8;
typedef __attribute__((ext_vector_type(4))) float f32x4;
typedef __attribute__((ext_vector_type(4))) unsigned u32x4;

// ---- workspace layout (float units) ----
#define WS_BAR     0                       // 1024 uints (4 KB) flags, zeroed per launch
#define WS_WEFF_C  1024                    // 2048*10
#define WS_WEFF_X  (WS_WEFF_C + 20480)     // 2048*6
#define WS_BIAS_C  (WS_WEFF_X + 12288)     // 64*2048
#define WS_BIAS_X  (WS_BIAS_C + 131072)    // 64*2048
#define WS_HRING   (WS_BIAS_X + 131072)    // uints: 8 islands * 4 slots * 8192 = 262144
#define WS_WPACK   (WS_HRING + 262144)     // shorts: 4194304 -> 2097152 floats

__device__ __forceinline__ float sigm(float v) { return 1.f / (1.f + __expf(-v)); }

// device-scope coherent 32B load: bypass L1/L2 to the coherence point (sc0+sc1 =
// strongest scope), but as a NORMAL wide load -> coalesces across lanes.
// Wait is inside the asm block (rule: never split load and its waitcnt).
__device__ __forceinline__ void load32B_coh(const unsigned* p, u32x4& lo, u32x4& hi) {
    asm volatile("global_load_dwordx4 %0, %2, off sc0 sc1\n\t"
                 "global_load_dwordx4 %1, %2, off offset:16 sc0 sc1\n\t"
                 "s_waitcnt vmcnt(0)"
                 : "=&v"(lo), "=&v"(hi) : "v"(p) : "memory");
}

// ---------------- setup 1: effective input weights + per-batch bias (validated R1-R5) ----------------
__global__ void setup_weff_bias(const float* __restrict__ ctx,
                                const float* __restrict__ we_c, const float* __restrict__ be_c,
                                const float* __restrict__ we_x, const float* __restrict__ be_x,
                                const float* __restrict__ wih_c, const float* __restrict__ bih_c, const float* __restrict__ bhh_c,
                                const float* __restrict__ wih_x, const float* __restrict__ bih_x, const float* __restrict__ bhh_x,
                                float* __restrict__ weff_c_o, float* __restrict__ weff_x_o,
                                float* __restrict__ biasE_c_o, float* __restrict__ biasE_x_o)
{
    const int g = blockIdx.x;
    const int lstm = blockIdx.y;
    const int tid = threadIdx.x;
    const float* wih  = lstm ? wih_x : wih_c;
    const float* wemb = lstm ? we_x  : we_c;
    const float* bemb = lstm ? be_x  : be_c;
    const int NW = lstm ? 6 : 10;
    float* weff  = lstm ? weff_x_o  : weff_c_o;
    float* biasE = lstm ? biasE_x_o : biasE_c_o;
    const float* wg_ = wih + (size_t)g * 768;

    __shared__ float s_bias0;

    if (tid < NW) {
        float s = 0.f;
        for (int d = 0; d < 512; ++d) s = fmaf(wg_[d], wemb[d * NW + tid], s);
        weff[g * NW + tid] = s;
    }
    if (tid >= 64 && tid < 128) {
        int l = tid - 64;
        float s = 0.f;
        for (int i = 0; i < 8; ++i) { int d = l + i * 64; s = fmaf(wg_[d], bemb[d], s); }
        for (int m = 1; m < 64; m <<= 1) s += __shfl_xor(s, m);
        if (l == 0) s_bias0 = s;
    }
    __syncthreads();
    if (tid >= 128 && tid < 192) {
        int b = tid - 128;
        float s = s_bias0 + (lstm ? (bih_x[g] + bhh_x[g]) : (bih_c[g] + bhh_c[g]));
        const float* cb = ctx + b * 256;
        const float* wc = wg_ + 512;
        for (int c = 0; c < 256; ++c) s = fmaf(wc[c], cb[c], s);
        biasE[b * 2048 + g] = s;
    }
}

// ---------------- setup 2: pack W_hh into MFMA B-frag layout, bf16 hi/lo (validated R3-R5) ----------------
__global__ void setup_wpackF(const float* __restrict__ whh_c, const float* __restrict__ whh_x,
                             short* __restrict__ wpackF)
{
    int idx = blockIdx.x * 256 + threadIdx.x;      // 2^21 total
    int pos = idx & 511;
    int lane = pos >> 3, j = pos & 7;
    int kt4 = (idx >> 9) & 3;
    int q   = (idx >> 11) & 3;
    int wv  = (idx >> 13) & 3;
    int ub  = (idx >> 15) & 31;
    int lstm = (idx >> 20) & 1;
    int g = q * 512 + ub * 16 + (lane & 15);
    int k = wv * 128 + kt4 * 32 + (lane >> 4) * 8 + j;
    const float* whh = lstm ? whh_x : whh_c;
    float v = whh[(size_t)g * 512 + k];
    __hip_bfloat16 hi = __float2bfloat16(v);
    __hip_bfloat16 lo = __float2bfloat16(v - __bfloat162float(hi));
    size_t base = (size_t)(idx >> 9) * 1024 + pos;
    wpackF[base]       = __builtin_bit_cast(short, hi);
    wpackF[base + 512] = __builtin_bit_cast(short, lo);
}

// ---------------- main persistent kernel: 8 independent islands of 32 WGs (R5 protocol) ----------------
// Island = (lstm, bt): 32 WGs (one per ub) own a 16-batch slice end-to-end.
// Sync: per-island 32-flag line (epoch-numbered agent atomics, no reset), depth-4 h ring.
// h stores: agent-scope relaxed atomics (write-through to coherence point, validated R4/R5).
// h loads: WIDE coherent loads (dwordx4 sc0 sc1) -> coalesced at the coherence point.
__global__ __launch_bounds__(256, 2) void lstm_main(
    const float* __restrict__ x,
    const short* __restrict__ wpackF,
    const float* __restrict__ weff_c, const float* __restrict__ weff_x,
    const float* __restrict__ biasE_c, const float* __restrict__ biasE_x,
    unsigned* __restrict__ ring,
    unsigned* __restrict__ bar,
    const float* __restrict__ w_out_cmd, const float* __restrict__ b_out_cmd,
    const float* __restrict__ w_out_coord, const float* __restrict__ b_out_coord,
    float* __restrict__ pre_coord,
    float* __restrict__ out)
{
    __shared__ float lds_gp[4][4][16][17];      // [wv][q][b][u] partial gates
    __shared__ float x_lds[16][10];
    __shared__ float weff_lds[4][16][10];
    __shared__ float w_cmd_lds[32][16][11];     // [k&31][k>>5][j]
    __shared__ float w_coord_lds[32][16][7];

    const int tid = threadIdx.x;
    const int bid = blockIdx.x;
    const int lane = tid & 63;
    const int wv = tid >> 6;
    const int lstm = bid >> 7;
    const int ub = (bid >> 2) & 31;
    const int bt = bid & 3;
    const int island = lstm * 4 + bt;
    const int u0 = ub * 16, b0 = bt * 16;
    const int NW = lstm ? 6 : 10;
    const int xoff = lstm ? 10 : 0;
    const int u_l = tid & 15, b_l = tid >> 4;

    const float* weff  = lstm ? weff_x : weff_c;
    const float* biasE = lstm ? biasE_x : biasE_c;

    unsigned* flags = bar + island * 64;            // 32 flags, one 128B line
    unsigned* ring_isl = ring + island * 4 * 8192;  // 4 slots x 8192 uints

    const bool is_head = (ub < 16);                 // handles batch b0+ub of its lstm
    const int hbatch = b0 + ub;

    // ---- one-time: recurrent weight frags into registers/AGPRs ----
    const short* wb = wpackF + (size_t)(((lstm * 32 + ub) * 4 + wv) * 16) * 1024 + lane * 8;
    short8 W[4][4][2];
#pragma unroll
    for (int q = 0; q < 4; ++q)
#pragma unroll
        for (int k4 = 0; k4 < 4; ++k4) {
            W[q][k4][0] = *(const short8*)(wb + (q * 4 + k4) * 1024);
            W[q][k4][1] = *(const short8*)(wb + (q * 4 + k4) * 1024 + 512);
        }

    float biasr[4];
#pragma unroll
    for (int q = 0; q < 4; ++q)
        biasr[q] = biasE[(size_t)(b0 + b_l) * 2048 + q * 512 + u0 + u_l];

    for (int i = tid; i < 64 * NW; i += 256) {
        int r = i / NW, j = i - r * NW;
        weff_lds[r >> 4][r & 15][j] = weff[(size_t)((r >> 4) * 512 + u0 + (r & 15)) * NW + j];
    }
    if (lstm == 0 && is_head) {
        for (int i = tid; i < 5120; i += 256) {
            int k = i / 10, j = i - k * 10;
            w_cmd_lds[k & 31][k >> 5][j] = w_out_cmd[(size_t)j * 512 + k];
        }
    }
    if (lstm == 1 && is_head) {
        for (int i = tid; i < 3072; i += 256) {
            int k = i / 6, j = i - k * 6;
            w_coord_lds[k & 31][k >> 5][j] = w_out_coord[(size_t)j * 522 + k];
        }
    }

    float c_reg = 0.f;

    for (int t = 0; t <= TSTEPS; ++t) {
        // ---- x prefetch for step t (static input: issue before the poll) ----
        float xv = 0.f;
        int xb = 0, xj = 0;
        const bool hasx = (t < TSTEPS) && (tid < 16 * NW);
        if (hasx) {
            xb = tid / NW; xj = tid - xb * NW;
            xv = x[(size_t)((b0 + xb) * TSTEPS + t) * 16 + xoff + xj];
        }

        // ---- poll island flags >= t : h_{t-1} of all 32 producers is visible ----
        if (t > 0) {
            if (wv == 0) {
                const unsigned tgt = (unsigned)t;
                const int fl = lane & 31;
                while (true) {
                    unsigned v = __hip_atomic_load(&flags[fl], __ATOMIC_RELAXED, __HIP_MEMORY_SCOPE_AGENT);
                    if (__all((int)(v >= tgt))) break;
                }
            }
            __syncthreads();
            asm volatile("" ::: "memory");
            __builtin_amdgcn_sched_barrier(0);
        }

        if (t < TSTEPS) {
            // ---- A-frags: WIDE coherent loads of packed h_{t-1} (coalesced), unpack hi/lo ----
            short8 Ah[4], Al[4];
            if (t > 0) {
                const unsigned* rb = ring_isl + ((t + 3) & 3) * 8192 + lane * 8;
                const unsigned* p0 = rb + (wv * 4 + 0) * 512;
                const unsigned* p1 = rb + (wv * 4 + 1) * 512;
                const unsigned* p2 = rb + (wv * 4 + 2) * 512;
                const unsigned* p3 = rb + (wv * 4 + 3) * 512;
                u32x4 r0, r1, r2, r3, r4, r5, r6, r7;
                asm volatile(
                    "global_load_dwordx4 %0, %8, off sc0 sc1\n\t"
                    "global_load_dwordx4 %1, %8, off offset:16 sc0 sc1\n\t"
                    "global_load_dwordx4 %2, %9, off sc0 sc1\n\t"
                    "global_load_dwordx4 %3, %9, off offset:16 sc0 sc1\n\t"
                    "global_load_dwordx4 %4, %10, off sc0 sc1\n\t"
                    "global_load_dwordx4 %5, %10, off offset:16 sc0 sc1\n\t"
                    "global_load_dwordx4 %6, %11, off sc0 sc1\n\t"
                    "global_load_dwordx4 %7, %11, off offset:16 sc0 sc1\n\t"
                    "s_waitcnt vmcnt(0)"
                    : "=&v"(r0), "=&v"(r1), "=&v"(r2), "=&v"(r3),
                      "=&v"(r4), "=&v"(r5), "=&v"(r6), "=&v"(r7)
                    : "v"(p0), "v"(p1), "v"(p2), "v"(p3)
                    : "memory");
                unsigned uu[4][8];
#pragma unroll
                for (int e = 0; e < 4; ++e) {
                    uu[0][e] = r0[e]; uu[0][4 + e] = r1[e];
                    uu[1][e] = r2[e]; uu[1][4 + e] = r3[e];
                    uu[2][e] = r4[e]; uu[2][4 + e] = r5[e];
                    uu[3][e] = r6[e]; uu[3][4 + e] = r7[e];
                }
#pragma unroll
                for (int i = 0; i < 4; ++i) {
                    union { unsigned u[4]; short8 s; } ah, al;
                    ah.u[0] = __builtin_amdgcn_perm(uu[i][1], uu[i][0], 0x05040100u);
                    ah.u[1] = __builtin_amdgcn_perm(uu[i][3], uu[i][2], 0x05040100u);
                    ah.u[2] = __builtin_amdgcn_perm(uu[i][5], uu[i][4], 0x05040100u);
                    ah.u[3] = __builtin_amdgcn_perm(uu[i][7], uu[i][6], 0x05040100u);
                    al.u[0] = __builtin_amdgcn_perm(uu[i][1], uu[i][0], 0x07060302u);
                    al.u[1] = __builtin_amdgcn_perm(uu[i][3], uu[i][2], 0x07060302u);
                    al.u[2] = __builtin_amdgcn_perm(uu[i][5], uu[i][4], 0x07060302u);
                    al.u[3] = __builtin_amdgcn_perm(uu[i][7], uu[i][6], 0x07060302u);
                    Ah[i] = ah.s;
                    Al[i] = al.s;
                }
            }
            f32x4 C[4];
#pragma unroll
            for (int q = 0; q < 4; ++q) { C[q][0] = 0.f; C[q][1] = 0.f; C[q][2] = 0.f; C[q][3] = 0.f; }
            if (t > 0) {
#pragma unroll
                for (int q = 0; q < 4; ++q)
#pragma unroll
                    for (int i = 0; i < 4; ++i) {
                        C[q] = __builtin_amdgcn_mfma_f32_16x16x32_bf16(Ah[i], W[q][i][0], C[q], 0, 0, 0);
                        C[q] = __builtin_amdgcn_mfma_f32_16x16x32_bf16(Al[i], W[q][i][0], C[q], 0, 0, 0);
                        C[q] = __builtin_amdgcn_mfma_f32_16x16x32_bf16(Ah[i], W[q][i][1], C[q], 0, 0, 0);
                    }
            }
            if (hasx) x_lds[xb][xj] = xv;
#pragma unroll
            for (int q = 0; q < 4; ++q)
#pragma unroll
                for (int i = 0; i < 4; ++i)
                    lds_gp[wv][q][(lane >> 4) * 4 + i][lane & 15] = C[q][i];
            __syncthreads();

            float g4[4];
#pragma unroll
            for (int q = 0; q < 4; ++q) {
                float s = biasr[q];
                s += lds_gp[0][q][b_l][u_l] + lds_gp[1][q][b_l][u_l]
                   + lds_gp[2][q][b_l][u_l] + lds_gp[3][q][b_l][u_l];
                for (int j = 0; j < NW; ++j)
                    s = fmaf(weff_lds[q][u_l][j], x_lds[b_l][j], s);
                g4[q] = s;
            }
            float iv = sigm(g4[0]);
            float fv = sigm(g4[1]);
            float gv = tanhf(g4[2]);
            float ov = sigm(g4[3]);
            c_reg = fmaf(fv, c_reg, iv * gv);
            float hv = ov * tanhf(c_reg);
            __hip_bfloat16 hh = __float2bfloat16(hv);
            __hip_bfloat16 hl = __float2bfloat16(hv - __bfloat162float(hh));
            {
                int ug = u0 + u_l;
                int kt = ug >> 5, ko = ug & 31;
                unsigned pack = (unsigned)(unsigned short)__builtin_bit_cast(short, hh)
                              | ((unsigned)(unsigned short)__builtin_bit_cast(short, hl) << 16);
                unsigned idx = (unsigned)((t & 3) * 8192 + kt * 512
                             + ((ko >> 3) * 16 + b_l) * 8 + (ko & 7));
                __hip_atomic_store(&ring_isl[idx], pack, __ATOMIC_RELAXED, __HIP_MEMORY_SCOPE_AGENT);
            }
            // drain all waves' ring stores (syncthreads waits vmcnt(0) per wave), then publish
            __syncthreads();
            if (tid == 0)
                __hip_atomic_store(&flags[ub], (unsigned)(t + 1), __ATOMIC_RELAXED, __HIP_MEMORY_SCOPE_AGENT);
        }

        // ---- fused heads for tc = t-1 (island-local read, gated by this epoch's poll) ----
        if (t >= 1 && is_head) {
            const int tc = t - 1;
            const unsigned* rs = ring_isl + (tc & 3) * 8192;
            if (lstm == 0 && tid < 160) {
                int j = tid >> 4, l = tid & 15;
                float s = 0.f;
#pragma unroll
                for (int c = 0; c < 4; ++c) {
                    u32x4 lo, hi;
                    load32B_coh(rs + l * 512 + (c * 16 + ub) * 8, lo, hi);
                    unsigned uu[8] = { lo[0], lo[1], lo[2], lo[3], hi[0], hi[1], hi[2], hi[3] };
#pragma unroll
                    for (int e = 0; e < 8; ++e) {
                        float hf = __builtin_bit_cast(float, uu[e] << 16);
                        s = fmaf(hf, w_cmd_lds[c * 8 + e][l][j], s);
                    }
                }
                s += __shfl_xor(s, 1); s += __shfl_xor(s, 2);
                s += __shfl_xor(s, 4); s += __shfl_xor(s, 8);
                if (l == 0) out[(size_t)(hbatch * TSTEPS + tc) * 10 + j] = s + b_out_cmd[j];
            }
            if (lstm == 1 && tid < 96) {
                int j = tid >> 4, l = tid & 15;
                float s = 0.f;
#pragma unroll
                for (int c = 0; c < 4; ++c) {
                    u32x4 lo, hi;
                    load32B_coh(rs + l * 512 + (c * 16 + ub) * 8, lo, hi);
                    unsigned uu[8] = { lo[0], lo[1], lo[2], lo[3], hi[0], hi[1], hi[2], hi[3] };
#pragma unroll
                    for (int e = 0; e < 8; ++e) {
                        float hf = __builtin_bit_cast(float, uu[e] << 16);
                        s = fmaf(hf, w_coord_lds[c * 8 + e][l][j], s);
                    }
                }
                s += __shfl_xor(s, 1); s += __shfl_xor(s, 2);
                s += __shfl_xor(s, 4); s += __shfl_xor(s, 8);
                if (l == 0) pre_coord[(size_t)(hbatch * TSTEPS + tc) * 6 + j] = s + b_out_coord[j];
            }
        }
    }
}

// ---------------- post: coord output = tanh(scale * (pre + cmd-coupling)), in place ----------------
__global__ void coord_post(const float* __restrict__ w_oc,
                           const float* __restrict__ scale_p, float* __restrict__ out)
{
    int idx = blockIdx.x * 256 + threadIdx.x;
    if (idx >= 64 * TSTEPS * 6) return;
    int j = idx % 6, bt_ = idx / 6;
    float s = out[64 * TSTEPS * 10 + idx];
    const float* cmd = out + (size_t)bt_ * 10;
#pragma unroll
    for (int i = 0; i < 10; ++i) s = fmaf(cmd[i], w_oc[j * 522 + 512 + i], s);
    out[64 * TSTEPS * 10 + idx] = tanhf(s * scale_p[0]);
}

// ---------------- host launcher ----------------
extern "C" void kernel_launch(void* const* d_in, const int* in_sizes, int n_in,
                              void* d_out, int out_size, void* d_ws, size_t ws_size,
                              hipStream_t stream)
{
    const float* x            = (const float*)d_in[0];
    const float* context      = (const float*)d_in[1];
    const float* w_cmd_emb    = (const float*)d_in[2];
    const float* b_cmd_emb    = (const float*)d_in[3];
    const float* w_coord_emb  = (const float*)d_in[4];
    const float* b_coord_emb  = (const float*)d_in[5];
    const float* w_ih_cmd     = (const float*)d_in[6];
    const float* w_hh_cmd     = (const float*)d_in[7];
    const float* b_ih_cmd     = (const float*)d_in[8];
    const float* b_hh_cmd     = (const float*)d_in[9];
    const float* w_ih_coord   = (const float*)d_in[10];
    const float* w_hh_coord   = (const float*)d_in[11];
    const float* b_ih_coord   = (const float*)d_in[12];
    const float* b_hh_coord   = (const float*)d_in[13];
    const float* w_out_cmd    = (const float*)d_in[14];
    const float* b_out_cmd    = (const float*)d_in[15];
    const float* w_out_coord  = (const float*)d_in[16];
    const float* b_out_coord  = (const float*)d_in[17];
    const float* scale        = (const float*)d_in[18];

    float* ws  = (float*)d_ws;
    float* out = (float*)d_out;

    float* weff_c   = ws + WS_WEFF_C;
    float* weff_x   = ws + WS_WEFF_X;
    float* biasE_c  = ws + WS_BIAS_C;
    float* biasE_x  = ws + WS_BIAS_X;
    unsigned* ring  = (unsigned*)(ws + WS_HRING);
    short* wpackF   = (short*)(ws + WS_WPACK);
    unsigned* bar   = (unsigned*)ws;
    float* pre      = out + 64 * TSTEPS * 10;   // coord pre-activations live in out tail

    hipMemsetAsync(d_ws, 0, 4096, stream);      // zero flags every launch

    setup_weff_bias<<<dim3(2048, 2), 256, 0, stream>>>(
        context, w_cmd_emb, b_cmd_emb, w_coord_emb, b_coord_emb,
        w_ih_cmd, b_ih_cmd, b_hh_cmd,
        w_ih_coord, b_ih_coord, b_hh_coord,
        weff_c, weff_x, biasE_c, biasE_x);

    setup_wpackF<<<8192, 256, 0, stream>>>(w_hh_cmd, w_hh_coord, wpackF);

    void* args[] = {
        (void*)&x, (void*)&wpackF,
        (void*)&weff_c, (void*)&weff_x,
        (void*)&biasE_c, (void*)&biasE_x,
        (void*)&ring, (void*)&bar,
        (void*)&w_out_cmd, (void*)&b_out_cmd,
        (void*)&w_out_coord, (void*)&b_out_coord,
        (void*)&pre, (void*)&out
    };
    hipError_t ce = hipLaunchCooperativeKernel((const void*)lstm_main, dim3(256), dim3(256),
                                               args, 0, stream);
    if (ce != hipSuccess) {
        // plain launch: with __launch_bounds__(256,2) any 2 WGs fit per CU, so all
        // 256 blocks are co-resident on 256 CUs regardless of distribution.
        lstm_main<<<dim3(256), dim3(256), 0, stream>>>(
            x, wpackF, weff_c, weff_x, biasE_c, biasE_x, ring, bar,
            w_out_cmd, b_out_cmd, w_out_coord, b_out_coord, pre, out);
    }

    coord_post<<<1536, 256, 0, stream>>>(w_out_coord, scale, out);
}

// Round 8
// 3717.888 us; speedup vs baseline: 10.1514x; 1.2885x over previous
//
#include <hip/hip_runtime.h>
#include <hip/hip_bf16.h>
#include <math.h>

#define TSTEPS 1024

typedef __attribute__((ext_vector_type(8))) short short8;
typedef __attribute__((ext_vector_type(4))) float f32x4;
typedef __attribute__((ext_vector_type(4))) unsigned u32x4;

// ---- workspace layout (float units) ----
#define WS_BAR     0                       // unused (kept for layout stability)
#define WS_WEFF_C  1024
#define WS_WEFF_X  (WS_WEFF_C + 20480)
#define WS_BIAS_C  (WS_WEFF_X + 12288)
#define WS_BIAS_X  (WS_BIAS_C + 131072)
#define WS_HRING   (WS_BIAS_X + 131072)    // uints: 8 islands * 8 slots * 8192 = 524288 (2MB, memset/launch)
#define WS_WPACK   (WS_HRING + 524288)     // shorts: 4194304 -> 2097152 floats
#define WS_WHEAD   (WS_WPACK + 2097152)    // shorts: 16384 -> 8192 floats

__device__ __forceinline__ float sigm(float v) { return 1.f / (1.f + __expf(-v)); }

// LDS-only barrier: order ds ops without draining in-flight global stores.
__device__ __forceinline__ void bar_lds() {
    asm volatile("s_waitcnt lgkmcnt(0)\n\ts_barrier" ::: "memory");
}

// ---------------- setup 1: effective input weights + per-batch bias (validated R1-R7) ----------------
__global__ void setup_weff_bias(const float* __restrict__ ctx,
                                const float* __restrict__ we_c, const float* __restrict__ be_c,
                                const float* __restrict__ we_x, const float* __restrict__ be_x,
                                const float* __restrict__ wih_c, const float* __restrict__ bih_c, const float* __restrict__ bhh_c,
                                const float* __restrict__ wih_x, const float* __restrict__ bih_x, const float* __restrict__ bhh_x,
                                float* __restrict__ weff_c_o, float* __restrict__ weff_x_o,
                                float* __restrict__ biasE_c_o, float* __restrict__ biasE_x_o)
{
    const int g = blockIdx.x;
    const int lstm = blockIdx.y;
    const int tid = threadIdx.x;
    const float* wih  = lstm ? wih_x : wih_c;
    const float* wemb = lstm ? we_x  : we_c;
    const float* bemb = lstm ? be_x  : be_c;
    const int NW = lstm ? 6 : 10;
    float* weff  = lstm ? weff_x_o  : weff_c_o;
    float* biasE = lstm ? biasE_x_o : biasE_c_o;
    const float* wg_ = wih + (size_t)g * 768;

    __shared__ float s_bias0;

    if (tid < NW) {
        float s = 0.f;
        for (int d = 0; d < 512; ++d) s = fmaf(wg_[d], wemb[d * NW + tid], s);
        weff[g * NW + tid] = s;
    }
    if (tid >= 64 && tid < 128) {
        int l = tid - 64;
        float s = 0.f;
        for (int i = 0; i < 8; ++i) { int d = l + i * 64; s = fmaf(wg_[d], bemb[d], s); }
        for (int m = 1; m < 64; m <<= 1) s += __shfl_xor(s, m);
        if (l == 0) s_bias0 = s;
    }
    __syncthreads();
    if (tid >= 128 && tid < 192) {
        int b = tid - 128;
        float s = s_bias0 + (lstm ? (bih_x[g] + bhh_x[g]) : (bih_c[g] + bhh_c[g]));
        const float* cb = ctx + b * 256;
        const float* wc = wg_ + 512;
        for (int c = 0; c < 256; ++c) s = fmaf(wc[c], cb[c], s);
        biasE[b * 2048 + g] = s;
    }
}

// ---------------- setup 2: pack W_hh into MFMA B-frag layout, bf16 hi/lo (validated R3-R7) ----------------
__global__ void setup_wpackF(const float* __restrict__ whh_c, const float* __restrict__ whh_x,
                             short* __restrict__ wpackF)
{
    int idx = blockIdx.x * 256 + threadIdx.x;      // 2^21 total
    int pos = idx & 511;
    int lane = pos >> 3, j = pos & 7;
    int kt4 = (idx >> 9) & 3;
    int q   = (idx >> 11) & 3;
    int wv  = (idx >> 13) & 3;
    int ub  = (idx >> 15) & 31;
    int lstm = (idx >> 20) & 1;
    int g = q * 512 + ub * 16 + (lane & 15);
    int k = wv * 128 + kt4 * 32 + (lane >> 4) * 8 + j;
    const float* whh = lstm ? whh_x : whh_c;
    float v = whh[(size_t)g * 512 + k];
    __hip_bfloat16 hi = __float2bfloat16(v);
    __hip_bfloat16 lo = __float2bfloat16(v - __bfloat162float(hi));
    size_t base = (size_t)(idx >> 9) * 1024 + pos;
    wpackF[base]       = __builtin_bit_cast(short, hi);
    wpackF[base + 512] = __builtin_bit_cast(short, lo);
}

// ---------------- setup 3: pack head weights into B-frag layout (hi only) ----------------
// layout: [lstm][wv(4)][k4(4)][512]; value = W_out[row j=lane&15][k], j>=NJ -> 0
__global__ void setup_wheadF(const float* __restrict__ w_out_cmd,
                             const float* __restrict__ w_out_coord,
                             short* __restrict__ wheadF)
{
    int idx = blockIdx.x * 256 + threadIdx.x;      // 16384 total
    int lstm = idx >> 13;
    int rest = idx & 8191;
    int wv = rest >> 11;
    int k4 = (rest >> 9) & 3;
    int pos = rest & 511;
    int lane = pos >> 3, jj = pos & 7;
    int j = lane & 15;
    int k = wv * 128 + k4 * 32 + (lane >> 4) * 8 + jj;
    int NJ = lstm ? 6 : 10;
    float v = 0.f;
    if (j < NJ) v = lstm ? w_out_coord[(size_t)j * 522 + k] : w_out_cmd[(size_t)j * 512 + k];
    wheadF[idx] = __builtin_bit_cast(short, __float2bfloat16(v));
}

// ---------------- main persistent kernel: flagless epoch-tagged data polling ----------------
// Island = (lstm, bt): 32 WGs. Ring: depth 8, packed uint per h value:
// bits0-15 = bf16 hi, bits16-31 = bf16 lo with its 2 LSBs REPLACED by tag = 1+((t>>3)&1).
// Consumers retry wide coherent loads until all words carry the expected tag -> sync==data, 1 RT.
// Producers: relaxed agent atomic stores, NO flag, NO drain. LDS barriers are lgkm-only.
// Heads: ub==0 WG computes cmd/coord head via 4 extra MFMAs on its own A-frags (hi-only).
__global__ __launch_bounds__(256, 2) void lstm_main(
    const float* __restrict__ x,
    const short* __restrict__ wpackF,
    const short* __restrict__ wheadF,
    const float* __restrict__ weff_c, const float* __restrict__ weff_x,
    const float* __restrict__ biasE_c, const float* __restrict__ biasE_x,
    unsigned* __restrict__ ring,
    const float* __restrict__ b_out_cmd, const float* __restrict__ b_out_coord,
    float* __restrict__ pre_coord,
    float* __restrict__ out)
{
    __shared__ float lds_gp[4][4][16][17];      // [wv][q][b][u] gate partials
    __shared__ float lds_hp[4][16][17];         // [wv][b][j]    head partials
    __shared__ float x_lds[16][10];
    __shared__ float weff_lds[4][16][10];
    __shared__ short whd_lds[4][4][512];        // head B-frags [wv][k4][...]

    const int tid = threadIdx.x;
    const int bid = blockIdx.x;
    const int lane = tid & 63;
    const int wv = tid >> 6;
    const int lstm = bid >> 7;
    const int ub = (bid >> 2) & 31;
    const int bt = bid & 3;
    const int island = lstm * 4 + bt;
    const int u0 = ub * 16, b0 = bt * 16;
    const int NW = lstm ? 6 : 10;
    const int xoff = lstm ? 10 : 0;
    const int u_l = tid & 15, b_l = tid >> 4;

    const float* weff  = lstm ? weff_x : weff_c;
    const float* biasE = lstm ? biasE_x : biasE_c;

    unsigned* ring_isl = ring + island * 8 * 8192;   // 8 slots x 8192 uints

    // ---- one-time: recurrent weight frags into registers/AGPRs ----
    const short* wb = wpackF + (size_t)(((lstm * 32 + ub) * 4 + wv) * 16) * 1024 + lane * 8;
    short8 W[4][4][2];
#pragma unroll
    for (int q = 0; q < 4; ++q)
#pragma unroll
        for (int k4 = 0; k4 < 4; ++k4) {
            W[q][k4][0] = *(const short8*)(wb + (q * 4 + k4) * 1024);
            W[q][k4][1] = *(const short8*)(wb + (q * 4 + k4) * 1024 + 512);
        }

    float biasr[4];
#pragma unroll
    for (int q = 0; q < 4; ++q)
        biasr[q] = biasE[(size_t)(b0 + b_l) * 2048 + q * 512 + u0 + u_l];

    for (int i = tid; i < 64 * NW; i += 256) {
        int r = i / NW, j = i - r * NW;
        weff_lds[r >> 4][r & 15][j] = weff[(size_t)((r >> 4) * 512 + u0 + (r & 15)) * NW + j];
    }

    // head bias + head weight frags (ub==0 WGs only use them, stage anyway if ub==0)
    float hbias = 0.f;
    const int NJ = lstm ? 6 : 10;
    if (ub == 0) {
        if (u_l < NJ) hbias = lstm ? b_out_coord[u_l] : b_out_cmd[u_l];
        const short* src = wheadF + lstm * 8192;
        short* dst = &whd_lds[0][0][0];
        for (int i = tid; i < 8192; i += 256) dst[i] = src[i];
    }

    float c_reg = 0.f;
    __syncthreads();   // one-time staging barrier

    for (int t = 0; t <= TSTEPS; ++t) {
        const bool last = (t == TSTEPS);
        if (last && ub != 0) break;   // only head-writer WGs run the final head-only step

        // ---- x prefetch for step t (static input; drained by the retry-load's vmcnt) ----
        float xv = 0.f;
        int xb = 0, xj = 0;
        const bool hasx = !last && (tid < 16 * NW);
        if (hasx) {
            xb = tid / NW; xj = tid - xb * NW;
            xv = x[(size_t)((b0 + xb) * TSTEPS + t) * 16 + xoff + xj];
        }

        // ---- A-frags: epoch-tagged retry load of h_{t-1} (sync == data, one RT) ----
        short8 Ah[4], Al[4];
        if (t > 0) {
            const unsigned rtag = 1u + (((unsigned)(t - 1) >> 3) & 1u);
            const unsigned* rb = ring_isl + ((t + 7) & 7) * 8192 + lane * 8;
            const unsigned* p0 = rb + (wv * 4 + 0) * 512;
            const unsigned* p1 = rb + (wv * 4 + 1) * 512;
            const unsigned* p2 = rb + (wv * 4 + 2) * 512;
            const unsigned* p3 = rb + (wv * 4 + 3) * 512;
            u32x4 r0, r1, r2, r3, r4, r5, r6, r7;
            while (true) {
                asm volatile(
                    "global_load_dwordx4 %0, %8, off sc0 sc1\n\t"
                    "global_load_dwordx4 %1, %8, off offset:16 sc0 sc1\n\t"
                    "global_load_dwordx4 %2, %9, off sc0 sc1\n\t"
                    "global_load_dwordx4 %3, %9, off offset:16 sc0 sc1\n\t"
                    "global_load_dwordx4 %4, %10, off sc0 sc1\n\t"
                    "global_load_dwordx4 %5, %10, off offset:16 sc0 sc1\n\t"
                    "global_load_dwordx4 %6, %11, off sc0 sc1\n\t"
                    "global_load_dwordx4 %7, %11, off offset:16 sc0 sc1\n\t"
                    "s_waitcnt vmcnt(0)"
                    : "=&v"(r0), "=&v"(r1), "=&v"(r2), "=&v"(r3),
                      "=&v"(r4), "=&v"(r5), "=&v"(r6), "=&v"(r7)
                    : "v"(p0), "v"(p1), "v"(p2), "v"(p3)
                    : "memory");
                bool ok = true;
#pragma unroll
                for (int e = 0; e < 4; ++e) {
                    ok = ok && (((r0[e] >> 16) & 3u) == rtag) && (((r1[e] >> 16) & 3u) == rtag)
                            && (((r2[e] >> 16) & 3u) == rtag) && (((r3[e] >> 16) & 3u) == rtag)
                            && (((r4[e] >> 16) & 3u) == rtag) && (((r5[e] >> 16) & 3u) == rtag)
                            && (((r6[e] >> 16) & 3u) == rtag) && (((r7[e] >> 16) & 3u) == rtag);
                }
                if (__all((int)ok)) break;
            }
            unsigned uu[4][8];
#pragma unroll
            for (int e = 0; e < 4; ++e) {
                uu[0][e] = r0[e]; uu[0][4 + e] = r1[e];
                uu[1][e] = r2[e]; uu[1][4 + e] = r3[e];
                uu[2][e] = r4[e]; uu[2][4 + e] = r5[e];
                uu[3][e] = r6[e]; uu[3][4 + e] = r7[e];
            }
#pragma unroll
            for (int i = 0; i < 4; ++i) {
                union { unsigned u[4]; short8 s; } ah, al;
                ah.u[0] = __builtin_amdgcn_perm(uu[i][1], uu[i][0], 0x05040100u);
                ah.u[1] = __builtin_amdgcn_perm(uu[i][3], uu[i][2], 0x05040100u);
                ah.u[2] = __builtin_amdgcn_perm(uu[i][5], uu[i][4], 0x05040100u);
                ah.u[3] = __builtin_amdgcn_perm(uu[i][7], uu[i][6], 0x05040100u);
                al.u[0] = __builtin_amdgcn_perm(uu[i][1], uu[i][0], 0x07060302u);
                al.u[1] = __builtin_amdgcn_perm(uu[i][3], uu[i][2], 0x07060302u);
                al.u[2] = __builtin_amdgcn_perm(uu[i][5], uu[i][4], 0x07060302u);
                al.u[3] = __builtin_amdgcn_perm(uu[i][7], uu[i][6], 0x07060302u);
                Ah[i] = ah.s;
                Al[i] = al.s;
            }
        }

        // ---- gates MFMA ----
        if (!last) {
            f32x4 C[4];
#pragma unroll
            for (int q = 0; q < 4; ++q) { C[q][0] = 0.f; C[q][1] = 0.f; C[q][2] = 0.f; C[q][3] = 0.f; }
            if (t > 0) {
#pragma unroll
                for (int q = 0; q < 4; ++q)
#pragma unroll
                    for (int i = 0; i < 4; ++i) {
                        C[q] = __builtin_amdgcn_mfma_f32_16x16x32_bf16(Ah[i], W[q][i][0], C[q], 0, 0, 0);
                        C[q] = __builtin_amdgcn_mfma_f32_16x16x32_bf16(Al[i], W[q][i][0], C[q], 0, 0, 0);
                        C[q] = __builtin_amdgcn_mfma_f32_16x16x32_bf16(Ah[i], W[q][i][1], C[q], 0, 0, 0);
                    }
            }
#pragma unroll
            for (int q = 0; q < 4; ++q)
#pragma unroll
                for (int i = 0; i < 4; ++i)
                    lds_gp[wv][q][(lane >> 4) * 4 + i][lane & 15] = C[q][i];
        }

        // ---- head MFMA (writer WG only): reuses this WG's A-frags, hi-only ----
        if (ub == 0 && t > 0) {
            short8 Whd[4];
#pragma unroll
            for (int i = 0; i < 4; ++i)
                Whd[i] = *(const short8*)&whd_lds[wv][i][lane * 8];
            f32x4 Ch; Ch[0] = 0.f; Ch[1] = 0.f; Ch[2] = 0.f; Ch[3] = 0.f;
#pragma unroll
            for (int i = 0; i < 4; ++i)
                Ch = __builtin_amdgcn_mfma_f32_16x16x32_bf16(Ah[i], Whd[i], Ch, 0, 0, 0);
#pragma unroll
            for (int i = 0; i < 4; ++i)
                lds_hp[wv][(lane >> 4) * 4 + i][lane & 15] = Ch[i];
        }

        if (hasx) x_lds[xb][xj] = xv;
        bar_lds();   // join: partials + x visible

        // ---- gate epilogue + cell update + tagged ring store ----
        if (!last) {
            float g4[4];
#pragma unroll
            for (int q = 0; q < 4; ++q) {
                float s = biasr[q];
                s += lds_gp[0][q][b_l][u_l] + lds_gp[1][q][b_l][u_l]
                   + lds_gp[2][q][b_l][u_l] + lds_gp[3][q][b_l][u_l];
                for (int j = 0; j < NW; ++j)
                    s = fmaf(weff_lds[q][u_l][j], x_lds[b_l][j], s);
                g4[q] = s;
            }
            float iv = sigm(g4[0]);
            float fv = sigm(g4[1]);
            float gv = tanhf(g4[2]);
            float ov = sigm(g4[3]);
            c_reg = fmaf(fv, c_reg, iv * gv);
            float hv = ov * tanhf(c_reg);
            __hip_bfloat16 hh = __float2bfloat16(hv);
            __hip_bfloat16 hl = __float2bfloat16(hv - __bfloat162float(hh));
            {
                const unsigned wtag = 1u + (((unsigned)t >> 3) & 1u);
                int ug = u0 + u_l;
                int kt = ug >> 5, ko = ug & 31;
                unsigned pack = (unsigned)(unsigned short)__builtin_bit_cast(short, hh)
                              | ((unsigned)(unsigned short)__builtin_bit_cast(short, hl) << 16);
                pack = (pack & ~0x00030000u) | (wtag << 16);
                unsigned idx = (unsigned)((t & 7) * 8192 + kt * 512
                             + ((ko >> 3) * 16 + b_l) * 8 + (ko & 7));
                __hip_atomic_store(&ring_isl[idx], pack, __ATOMIC_RELAXED, __HIP_MEMORY_SCOPE_AGENT);
            }
        }

        // ---- head epilogue (writer WG): h_{t-1} heads, no extra loads ----
        if (ub == 0 && t > 0 && u_l < NJ) {
            float hs = lds_hp[0][b_l][u_l] + lds_hp[1][b_l][u_l]
                     + lds_hp[2][b_l][u_l] + lds_hp[3][b_l][u_l] + hbias;
            const int tc = t - 1;
            if (lstm == 0)
                out[(size_t)((b0 + b_l) * TSTEPS + tc) * 10 + u_l] = hs;
            else
                pre_coord[(size_t)((b0 + b_l) * TSTEPS + tc) * 6 + u_l] = hs;
        }

        bar_lds();   // protect LDS reuse before next iteration's writes
    }
}

// ---------------- post: coord output = tanh(scale * (pre + cmd-coupling)), in place ----------------
__global__ void coord_post(const float* __restrict__ w_oc,
                           const float* __restrict__ scale_p, float* __restrict__ out)
{
    int idx = blockIdx.x * 256 + threadIdx.x;
    if (idx >= 64 * TSTEPS * 6) return;
    int j = idx % 6, bt_ = idx / 6;
    float s = out[64 * TSTEPS * 10 + idx];
    const float* cmd = out + (size_t)bt_ * 10;
#pragma unroll
    for (int i = 0; i < 10; ++i) s = fmaf(cmd[i], w_oc[j * 522 + 512 + i], s);
    out[64 * TSTEPS * 10 + idx] = tanhf(s * scale_p[0]);
}

// ---------------- host launcher ----------------
extern "C" void kernel_launch(void* const* d_in, const int* in_sizes, int n_in,
                              void* d_out, int out_size, void* d_ws, size_t ws_size,
                              hipStream_t stream)
{
    const float* x            = (const float*)d_in[0];
    const float* context      = (const float*)d_in[1];
    const float* w_cmd_emb    = (const float*)d_in[2];
    const float* b_cmd_emb    = (const float*)d_in[3];
    const float* w_coord_emb  = (const float*)d_in[4];
    const float* b_coord_emb  = (const float*)d_in[5];
    const float* w_ih_cmd     = (const float*)d_in[6];
    const float* w_hh_cmd     = (const float*)d_in[7];
    const float* b_ih_cmd     = (const float*)d_in[8];
    const float* b_hh_cmd     = (const float*)d_in[9];
    const float* w_ih_coord   = (const float*)d_in[10];
    const float* w_hh_coord   = (const float*)d_in[11];
    const float* b_ih_coord   = (const float*)d_in[12];
    const float* b_hh_coord   = (const float*)d_in[13];
    const float* w_out_cmd    = (const float*)d_in[14];
    const float* b_out_cmd    = (const float*)d_in[15];
    const float* w_out_coord  = (const float*)d_in[16];
    const float* b_out_coord  = (const float*)d_in[17];
    const float* scale        = (const float*)d_in[18];

    float* ws  = (float*)d_ws;
    float* out = (float*)d_out;

    float* weff_c   = ws + WS_WEFF_C;
    float* weff_x   = ws + WS_WEFF_X;
    float* biasE_c  = ws + WS_BIAS_C;
    float* biasE_x  = ws + WS_BIAS_X;
    unsigned* ring  = (unsigned*)(ws + WS_HRING);
    short* wpackF   = (short*)(ws + WS_WPACK);
    short* wheadF   = (short*)(ws + WS_WHEAD);
    float* pre      = out + 64 * TSTEPS * 10;   // coord pre-activations live in out tail

    // zero the h ring every launch: tag bits of zeroed words (=0) never match tags {1,2}
    hipMemsetAsync(ring, 0, 8 * 8 * 8192 * sizeof(unsigned), stream);

    setup_weff_bias<<<dim3(2048, 2), 256, 0, stream>>>(
        context, w_cmd_emb, b_cmd_emb, w_coord_emb, b_coord_emb,
        w_ih_cmd, b_ih_cmd, b_hh_cmd,
        w_ih_coord, b_ih_coord, b_hh_coord,
        weff_c, weff_x, biasE_c, biasE_x);

    setup_wpackF<<<8192, 256, 0, stream>>>(w_hh_cmd, w_hh_coord, wpackF);
    setup_wheadF<<<64, 256, 0, stream>>>(w_out_cmd, w_out_coord, wheadF);

    void* args[] = {
        (void*)&x, (void*)&wpackF, (void*)&wheadF,
        (void*)&weff_c, (void*)&weff_x,
        (void*)&biasE_c, (void*)&biasE_x,
        (void*)&ring,
        (void*)&b_out_cmd, (void*)&b_out_coord,
        (void*)&pre, (void*)&out
    };
    hipError_t ce = hipLaunchCooperativeKernel((const void*)lstm_main, dim3(256), dim3(256),
                                               args, 0, stream);
    if (ce != hipSuccess) {
        // plain launch: with __launch_bounds__(256,2) any 2 WGs fit per CU, so all
        // 256 blocks are co-resident on 256 CUs regardless of distribution.
        lstm_main<<<dim3(256), dim3(256), 0, stream>>>(
            x, wpackF, wheadF, weff_c, weff_x, biasE_c, biasE_x, ring,
            b_out_cmd, b_out_coord, pre, out);
    }

    coord_post<<<1536, 256, 0, stream>>>(w_out_coord, scale, out);
}